// Round 15
// baseline (452.695 us; speedup 1.0000x reference)
//
#include <hip/hip_runtime.h>
#include <hip/hip_bf16.h>

typedef __attribute__((ext_vector_type(8))) short short8;
typedef __attribute__((ext_vector_type(4))) float f32x4;

__device__ __forceinline__ ushort bf16_bits(float v) {
    __hip_bfloat16 h = __float2bfloat16(v);
    return *reinterpret_cast<ushort*>(&h);
}
__device__ __forceinline__ float bf16_val(float v) {
    __hip_bfloat16 h = __float2bfloat16(v);
    return __bfloat162float(h);
}
__device__ __forceinline__ float bfu_lo(uint u) {
    uint t = u << 16; return __uint_as_float(t);
}
__device__ __forceinline__ float bfu_hi(uint u) {
    uint t = u & 0xffff0000u; return __uint_as_float(t);
}

// ---------------- CSR build ----------------

__global__ __launch_bounds__(256) void k_count(const int* __restrict__ col,
                                               int* __restrict__ degi, int E) {
    int e = blockIdx.x * 256 + threadIdx.x;
    if (e < E) atomicAdd(&degi[col[e]], 1);
}

__global__ __launch_bounds__(256) void k_scan1(const int* __restrict__ degi,
                                               int* __restrict__ excl,
                                               int* __restrict__ bsum, int n) {
    int i = blockIdx.x * 256 + threadIdx.x;
    int v = (i < n) ? degi[i] : 0;
    int lane = threadIdx.x & 63, w = threadIdx.x >> 6;
    int s = v;
    #pragma unroll
    for (int o = 1; o < 64; o <<= 1) {
        int t = __shfl_up(s, o);
        if (lane >= o) s += t;
    }
    __shared__ int wsum[4];
    if (lane == 63) wsum[w] = s;
    __syncthreads();
    int add = 0;
    for (int ww = 0; ww < w; ww++) add += wsum[ww];
    int incl = s + add;
    if (i < n) excl[i] = incl - v;
    if (threadIdx.x == 255) bsum[blockIdx.x] = incl;
}

__global__ __launch_bounds__(256) void k_scan2(int* __restrict__ bsum, int nb) {
    int i = threadIdx.x;
    int v = (i < nb) ? bsum[i] : 0;
    int lane = i & 63, w = i >> 6;
    int s = v;
    #pragma unroll
    for (int o = 1; o < 64; o <<= 1) {
        int t = __shfl_up(s, o);
        if (lane >= o) s += t;
    }
    __shared__ int wsum[4];
    if (lane == 63) wsum[w] = s;
    __syncthreads();
    int add = 0;
    for (int ww = 0; ww < w; ww++) add += wsum[ww];
    if (i < nb) bsum[i] = (s + add) - v;
}

// rowptr/dis; also initializes per-group stage cursors (group = 8192 nodes,
// region start = rowptr[g*8192] — stage layout coincides with final CSR).
__global__ __launch_bounds__(256) void k_scan3(const int* __restrict__ excl,
                                               const int* __restrict__ bsum,
                                               const int* __restrict__ degi,
                                               int* __restrict__ rowptr,
                                               int* __restrict__ gcur,
                                               float* __restrict__ dis,
                                               int n, int E) {
    int i = blockIdx.x * 256 + threadIdx.x;
    if (i < n) {
        int p = excl[i] + bsum[blockIdx.x];
        rowptr[i] = p;
        if ((i & 8191) == 0) gcur[i >> 13] = p;
        int d = degi[i];
        dis[i] = d > 0 ? rsqrtf((float)d) : 0.f;
    }
    if (i == 0) rowptr[n] = E;
}

// Pass A: coarse-group edges (col>>13) into the stage array with block-level
// reservation (7 global atomics/block, no contention) + dense appends.
// Round-14 post-mortem: one-pass random 2B scatter writes ~42MB HBM (every
// store dirties a random 64B sector across non-coherent XCD L2s).
__global__ __launch_bounds__(256) void k_binA(const int* __restrict__ row,
                                              const int* __restrict__ col,
                                              int* __restrict__ gcur,
                                              uint* __restrict__ stage, int E) {
    __shared__ uint colbuf[2048];
    __shared__ int hist[8];
    __shared__ int lcur[8];
    int tid = threadIdx.x;
    int base = blockIdx.x * 2048;
    if (tid < 8) hist[tid] = 0;
    __syncthreads();
    #pragma unroll
    for (int i = 0; i < 8; i++) {
        int e = base + i * 256 + tid;
        uint c = 0xFFFFFFFFu;
        if (e < E) {
            c = (uint)col[e];
            atomicAdd(&hist[c >> 13], 1);
        }
        colbuf[i * 256 + tid] = c;
    }
    __syncthreads();
    if (tid < 7) lcur[tid] = atomicAdd(&gcur[tid], hist[tid]);
    __syncthreads();
    #pragma unroll
    for (int i = 0; i < 8; i++) {
        int idx = i * 256 + tid;
        uint c = colbuf[idx];
        if (c != 0xFFFFFFFFu) {
            uint r = (uint)row[base + idx];
            int p = atomicAdd(&lcur[c >> 13], 1);
            stage[p] = (c << 16) | r;
        }
    }
}

// Pass B: one block per 512-node bucket. Scans its parent group's stage slice
// (L2-hot), places rows via LDS cursors (bucket exclusively owned -> no global
// atomics), csr16 writes confined to a 16KB window (L1/L2-resident).
__global__ __launch_bounds__(256) void k_binB(const uint* __restrict__ stage,
                                              const int* __restrict__ rowptr,
                                              ushort* __restrict__ csr16, int n) {
    __shared__ int cur[512];
    int b = blockIdx.x;
    int lo = b << 9;
    int hi = min(lo + 512, n);
    int g = lo >> 13;
    int gstart = rowptr[g << 13];
    int gend = rowptr[min((g + 1) << 13, n)];
    for (int i = threadIdx.x; i < hi - lo; i += 256) cur[i] = rowptr[lo + i];
    __syncthreads();
    for (int idx = gstart + threadIdx.x; idx < gend; idx += 256) {
        uint pk = stage[idx];
        uint c = pk >> 16;
        if ((int)(c >> 9) == b) {
            int p = atomicAdd(&cur[c & 511], 1);
            csr16[p] = (ushort)(pk & 0xffffu);
        }
    }
}

// ---------------- input split: x -> bf16 hi/lo + dis-scaled gather copy ----------------

__global__ __launch_bounds__(256) void k_prepX(const float* __restrict__ x,
                                               const float* __restrict__ dis,
                                               ushort* __restrict__ xh,
                                               ushort* __restrict__ xl,
                                               ushort* __restrict__ xs, int total4) {
    int i = blockIdx.x * 256 + threadIdx.x;
    if (i >= total4) return;
    float4 v = reinterpret_cast<const float4*>(x)[i];
    float dn = dis[i >> 4];                  // node = (i*4)/64
    float vv[4] = {v.x, v.y, v.z, v.w};
    uint hv[2], lv[2], sv[2];
    #pragma unroll
    for (int g = 0; g < 2; g++) {
        float a0 = vv[g * 2], a1 = vv[g * 2 + 1];
        ushort h0 = bf16_bits(a0), l0 = bf16_bits(a0 - bf16_val(a0));
        ushort h1 = bf16_bits(a1), l1 = bf16_bits(a1 - bf16_val(a1));
        hv[g] = (uint)h0 | ((uint)h1 << 16);
        lv[g] = (uint)l0 | ((uint)l1 << 16);
        sv[g] = (uint)bf16_bits(a0 * dn) | ((uint)bf16_bits(a1 * dn) << 16);
    }
    reinterpret_cast<uint2*>(xh)[i] = make_uint2(hv[0], hv[1]);
    reinterpret_cast<uint2*>(xl)[i] = make_uint2(lv[0], lv[1]);
    reinterpret_cast<uint2*>(xs)[i] = make_uint2(sv[0], sv[1]);
}

// ---------------- CSR aggregations (gather, no atomics, U=8) ----------------

// agg[i] = dis[i] * sum_e xs[row_e]  (xs pre-scaled by dis[row]).
__global__ __launch_bounds__(256) void k_agg64_csr(const ushort* __restrict__ xs,
                                                   const int* __restrict__ rowptr,
                                                   const ushort* __restrict__ csr16,
                                                   const float* __restrict__ dis,
                                                   ushort* __restrict__ agghi,
                                                   ushort* __restrict__ agglo, int n) {
    int node = blockIdx.x * 8 + (threadIdx.x >> 5);
    if (node >= n) return;
    int lane = threadIdx.x & 31;           // half-wave lane: 2 dims per lane
    int s = rowptr[node], t = rowptr[node + 1];
    constexpr int U = 8;
    float2 acc = {0.f, 0.f};
    int p = s;
    for (; p + U <= t; p += U) {
        int rr[U];
        #pragma unroll
        for (int u = 0; u < U; u++) rr[u] = csr16[p + u];
        uint vv[U];
        #pragma unroll
        for (int u = 0; u < U; u++)
            vv[u] = *reinterpret_cast<const uint*>(&xs[(size_t)rr[u] * 64 + lane * 2]);
        #pragma unroll
        for (int u = 0; u < U; u++) {
            acc.x += bfu_lo(vv[u]);
            acc.y += bfu_hi(vv[u]);
        }
    }
    for (; p < t; ++p) {
        uint u = *reinterpret_cast<const uint*>(&xs[(size_t)csr16[p] * 64 + lane * 2]);
        acc.x += bfu_lo(u);
        acc.y += bfu_hi(u);
    }
    float dn = dis[node];
    acc.x *= dn; acc.y *= dn;
    float hx = bf16_val(acc.x), hy = bf16_val(acc.y);
    uint hpack = (uint)bf16_bits(acc.x) | ((uint)bf16_bits(acc.y) << 16);
    uint lpack = (uint)bf16_bits(acc.x - hx) | ((uint)bf16_bits(acc.y - hy) << 16);
    *reinterpret_cast<uint*>(&agghi[(size_t)node * 64 + lane * 2]) = hpack;
    *reinterpret_cast<uint*>(&agglo[(size_t)node * 64 + lane * 2]) = lpack;
}

// Fused: x7 = x5 + relu(dis[node] * (sum_e xw2[row_e]) + b2) in registers, then
//   out[node] = x7·w_fc2 + b_fc2 + b_conv3 ; xw3[node] = dis[node] * (x7·w_conv3)
__global__ __launch_bounds__(256) void k_agg128_x7dot(
    const ushort* __restrict__ xw,
    const int* __restrict__ rowptr,
    const ushort* __restrict__ csr16,
    const float* __restrict__ dis,
    const float* __restrict__ b2,
    const float* __restrict__ x5,
    const float* __restrict__ wfc2, const float* __restrict__ bfc2,
    const float* __restrict__ wc3,  const float* __restrict__ bc3,
    float* __restrict__ out, float* __restrict__ xw3, int n) {
    int node = blockIdx.x * 4 + (threadIdx.x >> 6);
    if (node >= n) return;
    int lane = threadIdx.x & 63;
    int s = rowptr[node], t = rowptr[node + 1];
    constexpr int U = 8;
    float2 acc = {0.f, 0.f};
    int p = s;
    for (; p + U <= t; p += U) {
        int rr[U];
        #pragma unroll
        for (int u = 0; u < U; u++) rr[u] = csr16[p + u];
        uint vv[U];
        #pragma unroll
        for (int u = 0; u < U; u++)
            vv[u] = *reinterpret_cast<const uint*>(&xw[(size_t)rr[u] * 128 + lane * 2]);
        #pragma unroll
        for (int u = 0; u < U; u++) {
            acc.x += bfu_lo(vv[u]);
            acc.y += bfu_hi(vv[u]);
        }
    }
    for (; p < t; ++p) {
        uint u = *reinterpret_cast<const uint*>(&xw[(size_t)csr16[p] * 128 + lane * 2]);
        acc.x += bfu_lo(u);
        acc.y += bfu_hi(u);
    }
    float dn = dis[node];
    float2 b = *reinterpret_cast<const float2*>(&b2[lane * 2]);
    float2 cur = *reinterpret_cast<const float2*>(&x5[(size_t)node * 128 + lane * 2]);
    cur.x += fmaxf(dn * acc.x + b.x, 0.f);     // x7, register-only
    cur.y += fmaxf(dn * acc.y + b.y, 0.f);

    float2 w1 = *reinterpret_cast<const float2*>(&wfc2[lane * 2]);
    float2 w2 = *reinterpret_cast<const float2*>(&wc3[lane * 2]);
    float s1 = cur.x * w1.x + cur.y * w1.y;
    float s2 = cur.x * w2.x + cur.y * w2.y;
    #pragma unroll
    for (int o = 32; o > 0; o >>= 1) {
        s1 += __shfl_down(s1, o);
        s2 += __shfl_down(s2, o);
    }
    if (lane == 0) {
        out[node] = s1 + bfc2[0] + bc3[0];
        xw3[node] = s2 * dn;                   // pre-scale for agg1
    }
}

__global__ __launch_bounds__(256) void k_agg1_csr(const float* __restrict__ sv,
                                                  const int* __restrict__ rowptr,
                                                  const ushort* __restrict__ csr16,
                                                  const float* __restrict__ dis,
                                                  float* __restrict__ out, int n) {
    int i = blockIdx.x * 256 + threadIdx.x;
    if (i >= n) return;
    int s = rowptr[i], t = rowptr[i + 1];
    float a = 0.f;
    #pragma unroll 4
    for (int p = s; p < t; ++p) a += sv[csr16[p]];
    out[i] += dis[i] * a;
}

// ---------------- weight fragment packing (single merged launch) ----------------
__global__ __launch_bounds__(256) void k_prepW(const float* __restrict__ w0,
                                               const float* __restrict__ w1,
                                               const float* __restrict__ wf1,
                                               const float* __restrict__ wf2,
                                               ushort* __restrict__ W0f,
                                               ushort* __restrict__ W1f,
                                               ushort* __restrict__ Bf) {
    int id = blockIdx.x * 256 + threadIdx.x;   // 8192 + 16384 = 24576
    if (id < 8192) {
        int mat = id >> 12;
        int rem = id & 4095;                   // arr*2048 + k0i*1024 + nt*64 + lane
        int lane = rem & 63;
        int nt = (rem >> 6) & 15;
        int k0i = (rem >> 10) & 1;
        int arr = rem >> 11;
        const float* w = mat ? w1 : w0;
        ushort* dst = mat ? W1f : W0f;
        int n = nt * 16 + (lane & 15);
        int kb = k0i * 32 + (lane >> 4) * 8;
        ushort o[8];
        #pragma unroll
        for (int j = 0; j < 8; j++) {
            float v = w[(size_t)(kb + j) * 256 + n];
            o[j] = arr ? bf16_bits(v - bf16_val(v)) : bf16_bits(v);
        }
        *reinterpret_cast<int4*>(&dst[(size_t)rem * 8]) = *reinterpret_cast<const int4*>(o);
    } else if (id < 24576) {
        int rem = id - 8192;                   // 16*16*64
        int lane = rem & 63;
        int nt   = (rem >> 6) & 15;
        int k0i  = (rem >> 10) & 15;
        int n = nt * 16 + (lane & 15);
        int kbase = k0i * 32 + (lane >> 4) * 8;
        ushort outv[8];
        #pragma unroll
        for (int j = 0; j < 8; j++) {
            int k = kbase + j;
            float v = (n < 128) ? wf1[(size_t)k * 128 + n]
                                : wf2[(size_t)k * 128 + (n - 128)];
            outv[j] = bf16_bits(v);
        }
        *reinterpret_cast<int4*>(&Bf[(size_t)rem * 8]) = *reinterpret_cast<const int4*>(outv);
    }
}

// ---------------- MFMA GEMMs ----------------

// K=64 dual-layer MFMA GEMM (blockIdx.y = layer): 3-term split inputs.
__global__ __launch_bounds__(256) void k_mm64(
    const ushort* __restrict__ xh, const ushort* __restrict__ xl,
    const ushort* __restrict__ ah_, const ushort* __restrict__ al_,
    const ushort* __restrict__ W0f, const ushort* __restrict__ W1f,
    const float* __restrict__ b0, const float* __restrict__ b1,
    ushort* __restrict__ Af, int M) {
    const int layer = blockIdx.y;
    const ushort* Ah = layer ? ah_ : xh;
    const ushort* Al = layer ? al_ : xl;
    const ushort* Wf = layer ? W1f : W0f;
    const float* bias = layer ? b1 : b0;
    const int colbase = layer * 256;

    const int t = threadIdx.x;
    const int lane = t & 63;
    const int wv = t >> 6;
    const int m0 = blockIdx.x * 64;
    const int ln15 = lane & 15;
    const int quad = lane >> 4;

    f32x4 acc[4][4] = {};

    #pragma unroll
    for (int k0i = 0; k0i < 2; k0i++) {
        short8 bh[4], bl[4];
        #pragma unroll
        for (int nt4 = 0; nt4 < 4; nt4++) {
            const ushort* pw = Wf + ((size_t)k0i * 16 + wv * 4 + nt4) * 512 + (size_t)lane * 8;
            bh[nt4] = *reinterpret_cast<const short8*>(pw);
            bl[nt4] = *reinterpret_cast<const short8*>(pw + 16384);   // arr=1 offset
        }
        #pragma unroll
        for (int mt = 0; mt < 4; mt++) {
            int gm = m0 + mt * 16 + ln15;
            int gmc = gm < M - 1 ? gm : M - 1;   // clamp: avoid OOB reads on tail rows
            size_t ia = (size_t)gmc * 64 + k0i * 32 + quad * 8;
            short8 ah = *reinterpret_cast<const short8*>(&Ah[ia]);
            short8 al = *reinterpret_cast<const short8*>(&Al[ia]);
            #pragma unroll
            for (int nt4 = 0; nt4 < 4; nt4++) {
                acc[mt][nt4] = __builtin_amdgcn_mfma_f32_16x16x32_bf16(ah, bh[nt4], acc[mt][nt4], 0, 0, 0);
                acc[mt][nt4] = __builtin_amdgcn_mfma_f32_16x16x32_bf16(ah, bl[nt4], acc[mt][nt4], 0, 0, 0);
                acc[mt][nt4] = __builtin_amdgcn_mfma_f32_16x16x32_bf16(al, bh[nt4], acc[mt][nt4], 0, 0, 0);
            }
        }
    }

    // epilogue: C layout col=lane&15, row=quad*4+r -> x3f fragment scatter (hi only)
    #pragma unroll
    for (int mt = 0; mt < 4; mt++) {
        #pragma unroll
        for (int nt4 = 0; nt4 < 4; nt4++) {
            int gn = wv * 64 + nt4 * 16 + ln15;      // local col 0..255
            int gcol = gn + colbase;                 // x3 col 0..511
            int k0f = gcol >> 5, qf = (gcol >> 3) & 3, j = gcol & 7;
            #pragma unroll
            for (int r = 0; r < 4; r++) {
                int gm = m0 + mt * 16 + quad * 4 + r;
                float v = fmaxf(acc[mt][nt4][r] + bias[gn], 0.f);
                size_t base = (((size_t)(gm >> 4)) * 16 + k0f) * 512 + (size_t)(qf * 16 + (gm & 15)) * 8 + j;
                Af[base] = bf16_bits(v);
            }
        }
    }
}

// LDS-free pure-bf16 MFMA dual GEMM, 32-row blocks, A and B register
// double-buffered.
__global__ __launch_bounds__(256) void k_gemm2_mfma(
    const ushort* __restrict__ Af, const ushort* __restrict__ Bf,
    const float* __restrict__ bias1, const float* __restrict__ dis,
    float* __restrict__ C1, ushort* __restrict__ C2, int M) {
    const int t = threadIdx.x;
    const int lane = t & 63;
    const int wv = t >> 6;
    const int mt0 = blockIdx.x * 2;          // two 16-row tiles per block
    const int ln15 = lane & 15;
    const int quad = lane >> 4;

    f32x4 acc[2][4] = {};

    const ushort* aPtr = Af + ((size_t)mt0 * 16) * 512 + (size_t)lane * 8;
    const ushort* bPtr = Bf + ((size_t)wv * 4) * 512 + (size_t)lane * 8;

    short8 aC[2], bC[4];
    #pragma unroll
    for (int mt = 0; mt < 2; mt++)
        aC[mt] = *reinterpret_cast<const short8*>(aPtr + (size_t)mt * 16 * 512);
    #pragma unroll
    for (int nt = 0; nt < 4; nt++)
        bC[nt] = *reinterpret_cast<const short8*>(bPtr + (size_t)nt * 512);

    for (int k0i = 0; k0i < 16; k0i++) {
        short8 aN[2], bN[4];
        if (k0i < 15) {
            #pragma unroll
            for (int mt = 0; mt < 2; mt++)
                aN[mt] = *reinterpret_cast<const short8*>(aPtr + ((size_t)mt * 16 + k0i + 1) * 512);
            #pragma unroll
            for (int nt = 0; nt < 4; nt++)
                bN[nt] = *reinterpret_cast<const short8*>(bPtr + ((size_t)(k0i + 1) * 16 + nt) * 512);
        }
        #pragma unroll
        for (int mt = 0; mt < 2; mt++)
            #pragma unroll
            for (int nt = 0; nt < 4; nt++)
                acc[mt][nt] = __builtin_amdgcn_mfma_f32_16x16x32_bf16(aC[mt], bC[nt], acc[mt][nt], 0, 0, 0);
        if (k0i < 15) {
            #pragma unroll
            for (int mt = 0; mt < 2; mt++) aC[mt] = aN[mt];
            #pragma unroll
            for (int nt = 0; nt < 4; nt++) bC[nt] = bN[nt];
        }
    }

    #pragma unroll
    for (int mt = 0; mt < 2; mt++) {
        float dn[4];
        #pragma unroll
        for (int r = 0; r < 4; r++) {
            int gm = (mt0 + mt) * 16 + quad * 4 + r;
            dn[r] = (gm < M) ? dis[gm] : 0.f;
        }
        #pragma unroll
        for (int nt = 0; nt < 4; nt++) {
            int gn = wv * 64 + nt * 16 + ln15;   // 0..255
            #pragma unroll
            for (int r = 0; r < 4; r++) {
                int gm = (mt0 + mt) * 16 + quad * 4 + r;
                if (gm >= M) continue;
                float v = acc[mt][nt][r];
                if (gn < 128) {
                    C1[(size_t)gm * 128 + gn] = fmaxf(v + bias1[gn], 0.f);
                } else {
                    C2[(size_t)gm * 128 + (gn - 128)] = bf16_bits(v * dn[r]);
                }
            }
        }
    }
}

extern "C" void kernel_launch(void* const* d_in, const int* in_sizes, int n_in,
                              void* d_out, int out_size, void* d_ws, size_t ws_size,
                              hipStream_t stream) {
    const float* x       = (const float*)d_in[0];
    const int*   ei      = (const int*)d_in[1];
    const float* w_fc    = (const float*)d_in[2];
    const float* b_fc    = (const float*)d_in[3];
    const float* w_conv1 = (const float*)d_in[4];
    const float* b_conv1 = (const float*)d_in[5];
    const float* w_fc1   = (const float*)d_in[6];
    const float* b_fc1   = (const float*)d_in[7];
    const float* w_conv2 = (const float*)d_in[8];
    const float* b_conv2 = (const float*)d_in[9];
    const float* w_fc2   = (const float*)d_in[10];
    const float* b_fc2   = (const float*)d_in[11];
    const float* w_conv3 = (const float*)d_in[12];
    const float* b_conv3 = (const float*)d_in[13];

    const int N = in_sizes[0] / 64;       // 50000
    const int E = in_sizes[1] / 2;        // 800000
    const int* row = ei;
    const int* col = ei + E;

    const int nb = (N + 255) / 256;
    const int nblk = (N + 63) / 64;       // 782  (64-row blocks, mm64)
    const int nblk2 = (N + 31) / 32;      // 1563 (32-row blocks, gemm2)
    const int Mt = nblk * 4;              // 3128 row-tiles of 16
    const int nbuckets = (N + 511) / 512; // 98

    // workspace layout. alloc() takes 4-BYTE units (chunks padded to 16B).
    char* p = (char*)d_ws;
    auto alloc = [&](size_t elems) {
        void* q = p; p += ((elems + 3) & ~(size_t)3) * 4; return q;
    };
    int*    degi    = (int*)   alloc(N);
    int*    excl    = (int*)   alloc(N);
    int*    bsum    = (int*)   alloc(256);
    int*    rowptr  = (int*)   alloc(N + 4);
    int*    gcur    = (int*)   alloc(8);
    uint*   stage   = (uint*)  alloc(E);                   // packed (col<<16|row)
    ushort* csr16   = (ushort*)alloc((size_t)E / 2);       // 2B row index per edge
    float*  dis     = (float*) alloc(N);
    ushort* xh      = (ushort*)alloc((size_t)N * 32);      // N*64 bf16 = N*32 words
    ushort* xl      = (ushort*)alloc((size_t)N * 32);
    ushort* xs      = (ushort*)alloc((size_t)N * 32);      // dis-scaled gather copy
    ushort* agghi   = (ushort*)alloc((size_t)N * 32);
    ushort* agglo   = (ushort*)alloc((size_t)N * 32);
    ushort* x3f     = (ushort*)alloc((size_t)Mt * 4096);   // hi only: Mt*16*64*8 ushorts
    ushort* Bf      = (ushort*)alloc(65536);               // single bf16
    ushort* W0f     = (ushort*)alloc(16384);
    ushort* W1f     = (ushort*)alloc(16384);
    float*  x5      = (float*) alloc((size_t)N * 128);
    ushort* xw2     = (ushort*)alloc((size_t)N * 64);      // N*128 bf16
    float*  xw3     = (float*) alloc(N);

    float* out = (float*)d_out;

    // ---- CSR build ----
    hipMemsetAsync(degi, 0, (size_t)N * sizeof(int), stream);
    k_count<<<(E + 255) / 256, 256, 0, stream>>>(col, degi, E);
    k_scan1<<<nb, 256, 0, stream>>>(degi, excl, bsum, N);
    k_scan2<<<1, 256, 0, stream>>>(bsum, nb);
    k_scan3<<<nb, 256, 0, stream>>>(excl, bsum, degi, rowptr, gcur, dis, N, E);
    k_binA<<<(E + 2047) / 2048, 256, 0, stream>>>(row, col, gcur, stage, E);
    k_binB<<<nbuckets, 256, 0, stream>>>(stage, rowptr, csr16, N);

    // input split (+dis-scaled copy) + weight fragment packing
    k_prepX<<<(N * 16 + 255) / 256, 256, 0, stream>>>(x, dis, xh, xl, xs, N * 16);
    k_prepW<<<24576 / 256, 256, 0, stream>>>(w_fc, w_conv1, w_fc1, w_conv2,
                                             W0f, W1f, Bf);

    // conv1 propagate: agg = dis[col] * sum xs[row], 2 nodes/wave
    k_agg64_csr<<<(N + 7) / 8, 256, 0, stream>>>(xs, rowptr, csr16, dis, agghi, agglo, N);

    // x1/x2 layers via MFMA -> x3f fragments (single bf16)
    k_mm64<<<dim3(nblk, 2), 256, 0, stream>>>(xh, xl, agghi, agglo, W0f, W1f,
                                              b_fc, b_conv1, x3f, N);

    // x5 = relu(x3 @ w_fc1 + b_fc1) ; xw2 = dis * (x3 @ w_conv2) (bf16 MFMA)
    k_gemm2_mfma<<<nblk2, 256, 0, stream>>>(x3f, Bf, b_fc1, dis, x5, xw2, N);

    // x7 in registers; fused dual dot -> out, xw3 (dis-scaled)
    k_agg128_x7dot<<<(N + 3) / 4, 256, 0, stream>>>(
        xw2, rowptr, csr16, dis, b_conv2, x5,
        w_fc2, b_fc2, w_conv3, b_conv3, out, xw3, N);

    // out += dis[i] * sum xw3[row]
    k_agg1_csr<<<(N + 255) / 256, 256, 0, stream>>>(xw3, rowptr, csr16, dis, out, N);
}

// Round 16
// 323.854 us; speedup vs baseline: 1.3978x; 1.3978x over previous
//
#include <hip/hip_runtime.h>
#include <hip/hip_bf16.h>

typedef __attribute__((ext_vector_type(8))) short short8;
typedef __attribute__((ext_vector_type(4))) float f32x4;

__device__ __forceinline__ ushort bf16_bits(float v) {
    __hip_bfloat16 h = __float2bfloat16(v);
    return *reinterpret_cast<ushort*>(&h);
}
__device__ __forceinline__ float bf16_val(float v) {
    __hip_bfloat16 h = __float2bfloat16(v);
    return __bfloat162float(h);
}
__device__ __forceinline__ float bfu_lo(uint u) {
    uint t = u << 16; return __uint_as_float(t);
}
__device__ __forceinline__ float bfu_hi(uint u) {
    uint t = u & 0xffff0000u; return __uint_as_float(t);
}

// ---------------- CSR build ----------------

__global__ __launch_bounds__(256) void k_count(const int* __restrict__ col,
                                               int* __restrict__ degi, int E) {
    int e = blockIdx.x * 256 + threadIdx.x;
    if (e < E) atomicAdd(&degi[col[e]], 1);
}

__global__ __launch_bounds__(256) void k_scan1(const int* __restrict__ degi,
                                               int* __restrict__ excl,
                                               int* __restrict__ bsum, int n) {
    int i = blockIdx.x * 256 + threadIdx.x;
    int v = (i < n) ? degi[i] : 0;
    int lane = threadIdx.x & 63, w = threadIdx.x >> 6;
    int s = v;
    #pragma unroll
    for (int o = 1; o < 64; o <<= 1) {
        int t = __shfl_up(s, o);
        if (lane >= o) s += t;
    }
    __shared__ int wsum[4];
    if (lane == 63) wsum[w] = s;
    __syncthreads();
    int add = 0;
    for (int ww = 0; ww < w; ww++) add += wsum[ww];
    int incl = s + add;
    if (i < n) excl[i] = incl - v;
    if (threadIdx.x == 255) bsum[blockIdx.x] = incl;
}

__global__ __launch_bounds__(256) void k_scan2(int* __restrict__ bsum, int nb) {
    int i = threadIdx.x;
    int v = (i < nb) ? bsum[i] : 0;
    int lane = i & 63, w = i >> 6;
    int s = v;
    #pragma unroll
    for (int o = 1; o < 64; o <<= 1) {
        int t = __shfl_up(s, o);
        if (lane >= o) s += t;
    }
    __shared__ int wsum[4];
    if (lane == 63) wsum[w] = s;
    __syncthreads();
    int add = 0;
    for (int ww = 0; ww < w; ww++) add += wsum[ww];
    if (i < nb) bsum[i] = (s + add) - v;
}

__global__ __launch_bounds__(256) void k_scan3(const int* __restrict__ excl,
                                               const int* __restrict__ bsum,
                                               const int* __restrict__ degi,
                                               int* __restrict__ rowptr,
                                               int* __restrict__ cursor,
                                               float* __restrict__ dis,
                                               int n, int E) {
    int i = blockIdx.x * 256 + threadIdx.x;
    if (i < n) {
        int p = excl[i] + bsum[blockIdx.x];
        rowptr[i] = p;
        cursor[i] = p;
        int d = degi[i];
        dis[i] = d > 0 ? rsqrtf((float)d) : 0.f;
    }
    if (i == 0) rowptr[n] = E;
}

// CSR slot scatter: 2-BYTE entry (norm factored out of the edge payload).
// (round-15 two-pass binning regressed 3.4x: 98-block pass B was
// latency-bound at 4% occupancy — single-pass scatter restored)
__global__ __launch_bounds__(256) void k_scatter(const int* __restrict__ row,
                                                 const int* __restrict__ col,
                                                 int* __restrict__ cursor,
                                                 ushort* __restrict__ csr16, int E) {
    int e = blockIdx.x * 256 + threadIdx.x;
    if (e >= E) return;
    int c = col[e], r = row[e];
    int p = atomicAdd(&cursor[c], 1);
    csr16[p] = (ushort)r;
}

// ---------------- input split: x -> bf16 hi/lo + dis-scaled gather copy ----------------

__global__ __launch_bounds__(256) void k_prepX(const float* __restrict__ x,
                                               const float* __restrict__ dis,
                                               ushort* __restrict__ xh,
                                               ushort* __restrict__ xl,
                                               ushort* __restrict__ xs, int total4) {
    int i = blockIdx.x * 256 + threadIdx.x;
    if (i >= total4) return;
    float4 v = reinterpret_cast<const float4*>(x)[i];
    float dn = dis[i >> 4];                  // node = (i*4)/64
    float vv[4] = {v.x, v.y, v.z, v.w};
    uint hv[2], lv[2], sv[2];
    #pragma unroll
    for (int g = 0; g < 2; g++) {
        float a0 = vv[g * 2], a1 = vv[g * 2 + 1];
        ushort h0 = bf16_bits(a0), l0 = bf16_bits(a0 - bf16_val(a0));
        ushort h1 = bf16_bits(a1), l1 = bf16_bits(a1 - bf16_val(a1));
        hv[g] = (uint)h0 | ((uint)h1 << 16);
        lv[g] = (uint)l0 | ((uint)l1 << 16);
        sv[g] = (uint)bf16_bits(a0 * dn) | ((uint)bf16_bits(a1 * dn) << 16);
    }
    reinterpret_cast<uint2*>(xh)[i] = make_uint2(hv[0], hv[1]);
    reinterpret_cast<uint2*>(xl)[i] = make_uint2(lv[0], lv[1]);
    reinterpret_cast<uint2*>(xs)[i] = make_uint2(sv[0], sv[1]);
}

// ---------------- CSR aggregations (gather, no atomics) ----------------

// agg[i] = dis[i] * sum_e xs[row_e]  (xs pre-scaled by dis[row]).
// TWO nodes per wave (half-wave each, uint = 2 bf16/lane), U=8.
__global__ __launch_bounds__(256) void k_agg64_csr(const ushort* __restrict__ xs,
                                                   const int* __restrict__ rowptr,
                                                   const ushort* __restrict__ csr16,
                                                   const float* __restrict__ dis,
                                                   ushort* __restrict__ agghi,
                                                   ushort* __restrict__ agglo, int n) {
    int node = blockIdx.x * 8 + (threadIdx.x >> 5);
    if (node >= n) return;
    int lane = threadIdx.x & 31;           // half-wave lane: 2 dims per lane
    int s = rowptr[node], t = rowptr[node + 1];
    constexpr int U = 8;
    float2 acc = {0.f, 0.f};
    int p = s;
    for (; p + U <= t; p += U) {
        int rr[U];
        #pragma unroll
        for (int u = 0; u < U; u++) rr[u] = csr16[p + u];
        uint vv[U];
        #pragma unroll
        for (int u = 0; u < U; u++)
            vv[u] = *reinterpret_cast<const uint*>(&xs[(size_t)rr[u] * 64 + lane * 2]);
        #pragma unroll
        for (int u = 0; u < U; u++) {
            acc.x += bfu_lo(vv[u]);
            acc.y += bfu_hi(vv[u]);
        }
    }
    for (; p < t; ++p) {
        uint u = *reinterpret_cast<const uint*>(&xs[(size_t)csr16[p] * 64 + lane * 2]);
        acc.x += bfu_lo(u);
        acc.y += bfu_hi(u);
    }
    float dn = dis[node];
    acc.x *= dn; acc.y *= dn;
    float hx = bf16_val(acc.x), hy = bf16_val(acc.y);
    uint hpack = (uint)bf16_bits(acc.x) | ((uint)bf16_bits(acc.y) << 16);
    uint lpack = (uint)bf16_bits(acc.x - hx) | ((uint)bf16_bits(acc.y - hy) << 16);
    *reinterpret_cast<uint*>(&agghi[(size_t)node * 64 + lane * 2]) = hpack;
    *reinterpret_cast<uint*>(&agglo[(size_t)node * 64 + lane * 2]) = lpack;
}

// Fused x7 + dual dot, WIDE-GRANULE gather (round-16): one wave per node;
// lane = sub(0..3)*16 + li(0..15); each lane loads uint4 (16B) of row
// csr16[p+sub] -> one instruction fetches 4 rows (1KB), 4x fewer requests
// than the 4B/lane layout (which was request-rate-bound at 2.7 TB/s).
// Slots combined at the end via shfl_xor(16/32).
__global__ __launch_bounds__(256) void k_agg128_x7dot(
    const ushort* __restrict__ xw,
    const int* __restrict__ rowptr,
    const ushort* __restrict__ csr16,
    const float* __restrict__ dis,
    const float* __restrict__ b2,
    const float* __restrict__ x5,
    const float* __restrict__ wfc2, const float* __restrict__ bfc2,
    const float* __restrict__ wc3,  const float* __restrict__ bc3,
    float* __restrict__ out, float* __restrict__ xw3, int n) {
    int node = blockIdx.x * 4 + (threadIdx.x >> 6);
    if (node >= n) return;
    int lane = threadIdx.x & 63;
    int sub = lane >> 4;          // edge slot 0..3
    int li  = lane & 15;          // dim group: dims li*8 .. li*8+7
    int s = rowptr[node], t = rowptr[node + 1];
    float acc[8] = {};
    int p = s;
    // main: 16 edges per iter (4 slots x unroll 4), 4KB in flight per wave
    for (; p + 16 <= t; p += 16) {
        int rr[4];
        #pragma unroll
        for (int u = 0; u < 4; u++) rr[u] = csr16[p + u * 4 + sub];
        uint4 v[4];
        #pragma unroll
        for (int u = 0; u < 4; u++)
            v[u] = *reinterpret_cast<const uint4*>(&xw[(size_t)rr[u] * 128 + li * 8]);
        #pragma unroll
        for (int u = 0; u < 4; u++) {
            acc[0] += bfu_lo(v[u].x); acc[1] += bfu_hi(v[u].x);
            acc[2] += bfu_lo(v[u].y); acc[3] += bfu_hi(v[u].y);
            acc[4] += bfu_lo(v[u].z); acc[5] += bfu_hi(v[u].z);
            acc[6] += bfu_lo(v[u].w); acc[7] += bfu_hi(v[u].w);
        }
    }
    // tail: 4 edges per iter, predicated per slot
    for (; p < t; p += 4) {
        int e = p + sub;
        if (e < t) {
            int rr = csr16[e];
            uint4 v = *reinterpret_cast<const uint4*>(&xw[(size_t)rr * 128 + li * 8]);
            acc[0] += bfu_lo(v.x); acc[1] += bfu_hi(v.x);
            acc[2] += bfu_lo(v.y); acc[3] += bfu_hi(v.y);
            acc[4] += bfu_lo(v.z); acc[5] += bfu_hi(v.z);
            acc[6] += bfu_lo(v.w); acc[7] += bfu_hi(v.w);
        }
    }
    // combine the 4 edge slots (lanes sharing li): xor over lane bits 4,5
    #pragma unroll
    for (int j = 0; j < 8; j++) {
        acc[j] += __shfl_xor(acc[j], 16);
        acc[j] += __shfl_xor(acc[j], 32);
    }
    float dn = dis[node];
    float s1 = 0.f, s2 = 0.f;
    if (sub == 0) {
        #pragma unroll
        for (int j = 0; j < 8; j++) {
            int d = li * 8 + j;
            float x7 = x5[(size_t)node * 128 + d] + fmaxf(dn * acc[j] + b2[d], 0.f);
            s1 += x7 * wfc2[d];
            s2 += x7 * wc3[d];
        }
    }
    #pragma unroll
    for (int o = 32; o > 0; o >>= 1) {
        s1 += __shfl_down(s1, o);
        s2 += __shfl_down(s2, o);
    }
    if (lane == 0) {
        out[node] = s1 + bfc2[0] + bc3[0];
        xw3[node] = s2 * dn;                   // pre-scale for agg1
    }
}

__global__ __launch_bounds__(256) void k_agg1_csr(const float* __restrict__ sv,
                                                  const int* __restrict__ rowptr,
                                                  const ushort* __restrict__ csr16,
                                                  const float* __restrict__ dis,
                                                  float* __restrict__ out, int n) {
    int i = blockIdx.x * 256 + threadIdx.x;
    if (i >= n) return;
    int s = rowptr[i], t = rowptr[i + 1];
    float a = 0.f;
    #pragma unroll 4
    for (int p = s; p < t; ++p) a += sv[csr16[p]];
    out[i] += dis[i] * a;
}

// ---------------- weight fragment packing (single merged launch) ----------------
__global__ __launch_bounds__(256) void k_prepW(const float* __restrict__ w0,
                                               const float* __restrict__ w1,
                                               const float* __restrict__ wf1,
                                               const float* __restrict__ wf2,
                                               ushort* __restrict__ W0f,
                                               ushort* __restrict__ W1f,
                                               ushort* __restrict__ Bf) {
    int id = blockIdx.x * 256 + threadIdx.x;   // 8192 + 16384 = 24576
    if (id < 8192) {
        int mat = id >> 12;
        int rem = id & 4095;                   // arr*2048 + k0i*1024 + nt*64 + lane
        int lane = rem & 63;
        int nt = (rem >> 6) & 15;
        int k0i = (rem >> 10) & 1;
        int arr = rem >> 11;
        const float* w = mat ? w1 : w0;
        ushort* dst = mat ? W1f : W0f;
        int n = nt * 16 + (lane & 15);
        int kb = k0i * 32 + (lane >> 4) * 8;
        ushort o[8];
        #pragma unroll
        for (int j = 0; j < 8; j++) {
            float v = w[(size_t)(kb + j) * 256 + n];
            o[j] = arr ? bf16_bits(v - bf16_val(v)) : bf16_bits(v);
        }
        *reinterpret_cast<int4*>(&dst[(size_t)rem * 8]) = *reinterpret_cast<const int4*>(o);
    } else if (id < 24576) {
        int rem = id - 8192;                   // 16*16*64
        int lane = rem & 63;
        int nt   = (rem >> 6) & 15;
        int k0i  = (rem >> 10) & 15;
        int n = nt * 16 + (lane & 15);
        int kbase = k0i * 32 + (lane >> 4) * 8;
        ushort outv[8];
        #pragma unroll
        for (int j = 0; j < 8; j++) {
            int k = kbase + j;
            float v = (n < 128) ? wf1[(size_t)k * 128 + n]
                                : wf2[(size_t)k * 128 + (n - 128)];
            outv[j] = bf16_bits(v);
        }
        *reinterpret_cast<int4*>(&Bf[(size_t)rem * 8]) = *reinterpret_cast<const int4*>(outv);
    }
}

// ---------------- MFMA GEMMs ----------------

// K=64 dual-layer MFMA GEMM (blockIdx.y = layer): 3-term split inputs.
__global__ __launch_bounds__(256) void k_mm64(
    const ushort* __restrict__ xh, const ushort* __restrict__ xl,
    const ushort* __restrict__ ah_, const ushort* __restrict__ al_,
    const ushort* __restrict__ W0f, const ushort* __restrict__ W1f,
    const float* __restrict__ b0, const float* __restrict__ b1,
    ushort* __restrict__ Af, int M) {
    const int layer = blockIdx.y;
    const ushort* Ah = layer ? ah_ : xh;
    const ushort* Al = layer ? al_ : xl;
    const ushort* Wf = layer ? W1f : W0f;
    const float* bias = layer ? b1 : b0;
    const int colbase = layer * 256;

    const int t = threadIdx.x;
    const int lane = t & 63;
    const int wv = t >> 6;
    const int m0 = blockIdx.x * 64;
    const int ln15 = lane & 15;
    const int quad = lane >> 4;

    f32x4 acc[4][4] = {};

    #pragma unroll
    for (int k0i = 0; k0i < 2; k0i++) {
        short8 bh[4], bl[4];
        #pragma unroll
        for (int nt4 = 0; nt4 < 4; nt4++) {
            const ushort* pw = Wf + ((size_t)k0i * 16 + wv * 4 + nt4) * 512 + (size_t)lane * 8;
            bh[nt4] = *reinterpret_cast<const short8*>(pw);
            bl[nt4] = *reinterpret_cast<const short8*>(pw + 16384);   // arr=1 offset
        }
        #pragma unroll
        for (int mt = 0; mt < 4; mt++) {
            int gm = m0 + mt * 16 + ln15;
            int gmc = gm < M - 1 ? gm : M - 1;   // clamp: avoid OOB reads on tail rows
            size_t ia = (size_t)gmc * 64 + k0i * 32 + quad * 8;
            short8 ah = *reinterpret_cast<const short8*>(&Ah[ia]);
            short8 al = *reinterpret_cast<const short8*>(&Al[ia]);
            #pragma unroll
            for (int nt4 = 0; nt4 < 4; nt4++) {
                acc[mt][nt4] = __builtin_amdgcn_mfma_f32_16x16x32_bf16(ah, bh[nt4], acc[mt][nt4], 0, 0, 0);
                acc[mt][nt4] = __builtin_amdgcn_mfma_f32_16x16x32_bf16(ah, bl[nt4], acc[mt][nt4], 0, 0, 0);
                acc[mt][nt4] = __builtin_amdgcn_mfma_f32_16x16x32_bf16(al, bh[nt4], acc[mt][nt4], 0, 0, 0);
            }
        }
    }

    // epilogue: C layout col=lane&15, row=quad*4+r -> x3f fragment scatter (hi only)
    #pragma unroll
    for (int mt = 0; mt < 4; mt++) {
        #pragma unroll
        for (int nt4 = 0; nt4 < 4; nt4++) {
            int gn = wv * 64 + nt4 * 16 + ln15;      // local col 0..255
            int gcol = gn + colbase;                 // x3 col 0..511
            int k0f = gcol >> 5, qf = (gcol >> 3) & 3, j = gcol & 7;
            #pragma unroll
            for (int r = 0; r < 4; r++) {
                int gm = m0 + mt * 16 + quad * 4 + r;
                float v = fmaxf(acc[mt][nt4][r] + bias[gn], 0.f);
                size_t base = (((size_t)(gm >> 4)) * 16 + k0f) * 512 + (size_t)(qf * 16 + (gm & 15)) * 8 + j;
                Af[base] = bf16_bits(v);
            }
        }
    }
}

// LDS-free pure-bf16 MFMA dual GEMM, 32-row blocks, A and B register
// double-buffered.
__global__ __launch_bounds__(256) void k_gemm2_mfma(
    const ushort* __restrict__ Af, const ushort* __restrict__ Bf,
    const float* __restrict__ bias1, const float* __restrict__ dis,
    float* __restrict__ C1, ushort* __restrict__ C2, int M) {
    const int t = threadIdx.x;
    const int lane = t & 63;
    const int wv = t >> 6;
    const int mt0 = blockIdx.x * 2;          // two 16-row tiles per block
    const int ln15 = lane & 15;
    const int quad = lane >> 4;

    f32x4 acc[2][4] = {};

    const ushort* aPtr = Af + ((size_t)mt0 * 16) * 512 + (size_t)lane * 8;
    const ushort* bPtr = Bf + ((size_t)wv * 4) * 512 + (size_t)lane * 8;

    short8 aC[2], bC[4];
    #pragma unroll
    for (int mt = 0; mt < 2; mt++)
        aC[mt] = *reinterpret_cast<const short8*>(aPtr + (size_t)mt * 16 * 512);
    #pragma unroll
    for (int nt = 0; nt < 4; nt++)
        bC[nt] = *reinterpret_cast<const short8*>(bPtr + (size_t)nt * 512);

    for (int k0i = 0; k0i < 16; k0i++) {
        short8 aN[2], bN[4];
        if (k0i < 15) {
            #pragma unroll
            for (int mt = 0; mt < 2; mt++)
                aN[mt] = *reinterpret_cast<const short8*>(aPtr + ((size_t)mt * 16 + k0i + 1) * 512);
            #pragma unroll
            for (int nt = 0; nt < 4; nt++)
                bN[nt] = *reinterpret_cast<const short8*>(bPtr + ((size_t)(k0i + 1) * 16 + nt) * 512);
        }
        #pragma unroll
        for (int mt = 0; mt < 2; mt++)
            #pragma unroll
            for (int nt = 0; nt < 4; nt++)
                acc[mt][nt] = __builtin_amdgcn_mfma_f32_16x16x32_bf16(aC[mt], bC[nt], acc[mt][nt], 0, 0, 0);
        if (k0i < 15) {
            #pragma unroll
            for (int mt = 0; mt < 2; mt++) aC[mt] = aN[mt];
            #pragma unroll
            for (int nt = 0; nt < 4; nt++) bC[nt] = bN[nt];
        }
    }

    #pragma unroll
    for (int mt = 0; mt < 2; mt++) {
        float dn[4];
        #pragma unroll
        for (int r = 0; r < 4; r++) {
            int gm = (mt0 + mt) * 16 + quad * 4 + r;
            dn[r] = (gm < M) ? dis[gm] : 0.f;
        }
        #pragma unroll
        for (int nt = 0; nt < 4; nt++) {
            int gn = wv * 64 + nt * 16 + ln15;   // 0..255
            #pragma unroll
            for (int r = 0; r < 4; r++) {
                int gm = (mt0 + mt) * 16 + quad * 4 + r;
                if (gm >= M) continue;
                float v = acc[mt][nt][r];
                if (gn < 128) {
                    C1[(size_t)gm * 128 + gn] = fmaxf(v + bias1[gn], 0.f);
                } else {
                    C2[(size_t)gm * 128 + (gn - 128)] = bf16_bits(v * dn[r]);
                }
            }
        }
    }
}

extern "C" void kernel_launch(void* const* d_in, const int* in_sizes, int n_in,
                              void* d_out, int out_size, void* d_ws, size_t ws_size,
                              hipStream_t stream) {
    const float* x       = (const float*)d_in[0];
    const int*   ei      = (const int*)d_in[1];
    const float* w_fc    = (const float*)d_in[2];
    const float* b_fc    = (const float*)d_in[3];
    const float* w_conv1 = (const float*)d_in[4];
    const float* b_conv1 = (const float*)d_in[5];
    const float* w_fc1   = (const float*)d_in[6];
    const float* b_fc1   = (const float*)d_in[7];
    const float* w_conv2 = (const float*)d_in[8];
    const float* b_conv2 = (const float*)d_in[9];
    const float* w_fc2   = (const float*)d_in[10];
    const float* b_fc2   = (const float*)d_in[11];
    const float* w_conv3 = (const float*)d_in[12];
    const float* b_conv3 = (const float*)d_in[13];

    const int N = in_sizes[0] / 64;       // 50000
    const int E = in_sizes[1] / 2;        // 800000
    const int* row = ei;
    const int* col = ei + E;

    const int nb = (N + 255) / 256;
    const int nblk = (N + 63) / 64;       // 782  (64-row blocks, mm64)
    const int nblk2 = (N + 31) / 32;      // 1563 (32-row blocks, gemm2)
    const int Mt = nblk * 4;              // 3128 row-tiles of 16

    // workspace layout. alloc() takes 4-BYTE units (chunks padded to 16B).
    char* p = (char*)d_ws;
    auto alloc = [&](size_t elems) {
        void* q = p; p += ((elems + 3) & ~(size_t)3) * 4; return q;
    };
    int*    degi    = (int*)   alloc(N);
    int*    excl    = (int*)   alloc(N);
    int*    bsum    = (int*)   alloc(256);
    int*    rowptr  = (int*)   alloc(N + 4);
    int*    cursor  = (int*)   alloc(N);
    ushort* csr16   = (ushort*)alloc((size_t)E / 2);       // 2B row index per edge
    float*  dis     = (float*) alloc(N);
    ushort* xh      = (ushort*)alloc((size_t)N * 32);      // N*64 bf16 = N*32 words
    ushort* xl      = (ushort*)alloc((size_t)N * 32);
    ushort* xs      = (ushort*)alloc((size_t)N * 32);      // dis-scaled gather copy
    ushort* agghi   = (ushort*)alloc((size_t)N * 32);
    ushort* agglo   = (ushort*)alloc((size_t)N * 32);
    ushort* x3f     = (ushort*)alloc((size_t)Mt * 4096);   // hi only: Mt*16*64*8 ushorts
    ushort* Bf      = (ushort*)alloc(65536);               // single bf16
    ushort* W0f     = (ushort*)alloc(16384);
    ushort* W1f     = (ushort*)alloc(16384);
    float*  x5      = (float*) alloc((size_t)N * 128);
    ushort* xw2     = (ushort*)alloc((size_t)N * 64);      // N*128 bf16
    float*  xw3     = (float*) alloc(N);

    float* out = (float*)d_out;

    // ---- CSR build ----
    hipMemsetAsync(degi, 0, (size_t)N * sizeof(int), stream);
    k_count<<<(E + 255) / 256, 256, 0, stream>>>(col, degi, E);
    k_scan1<<<nb, 256, 0, stream>>>(degi, excl, bsum, N);
    k_scan2<<<1, 256, 0, stream>>>(bsum, nb);
    k_scan3<<<nb, 256, 0, stream>>>(excl, bsum, degi, rowptr, cursor, dis, N, E);
    k_scatter<<<(E + 255) / 256, 256, 0, stream>>>(row, col, cursor, csr16, E);

    // input split (+dis-scaled copy) + weight fragment packing
    k_prepX<<<(N * 16 + 255) / 256, 256, 0, stream>>>(x, dis, xh, xl, xs, N * 16);
    k_prepW<<<24576 / 256, 256, 0, stream>>>(w_fc, w_conv1, w_fc1, w_conv2,
                                             W0f, W1f, Bf);

    // conv1 propagate: agg = dis[col] * sum xs[row], 2 nodes/wave
    k_agg64_csr<<<(N + 7) / 8, 256, 0, stream>>>(xs, rowptr, csr16, dis, agghi, agglo, N);

    // x1/x2 layers via MFMA -> x3f fragments (single bf16)
    k_mm64<<<dim3(nblk, 2), 256, 0, stream>>>(xh, xl, agghi, agglo, W0f, W1f,
                                              b_fc, b_conv1, x3f, N);

    // x5 = relu(x3 @ w_fc1 + b_fc1) ; xw2 = dis * (x3 @ w_conv2) (bf16 MFMA)
    k_gemm2_mfma<<<nblk2, 256, 0, stream>>>(x3f, Bf, b_fc1, dis, x5, xw2, N);

    // x7 in registers (wide-granule gather); fused dual dot -> out, xw3
    k_agg128_x7dot<<<(N + 3) / 4, 256, 0, stream>>>(
        xw2, rowptr, csr16, dis, b_conv2, x5,
        w_fc2, b_fc2, w_conv3, b_conv3, out, xw3, N);

    // out += dis[i] * sum xw3[row]
    k_agg1_csr<<<(N + 255) / 256, 256, 0, stream>>>(xw3, rowptr, csr16, dis, out, N);
}

// Round 17
// 310.189 us; speedup vs baseline: 1.4594x; 1.0441x over previous
//
#include <hip/hip_runtime.h>
#include <hip/hip_bf16.h>

typedef __attribute__((ext_vector_type(8))) short short8;
typedef __attribute__((ext_vector_type(4))) float f32x4;

__device__ __forceinline__ ushort bf16_bits(float v) {
    __hip_bfloat16 h = __float2bfloat16(v);
    return *reinterpret_cast<ushort*>(&h);
}
__device__ __forceinline__ float bf16_val(float v) {
    __hip_bfloat16 h = __float2bfloat16(v);
    return __bfloat162float(h);
}
__device__ __forceinline__ float bfu_lo(uint u) {
    uint t = u << 16; return __uint_as_float(t);
}
__device__ __forceinline__ float bfu_hi(uint u) {
    uint t = u & 0xffff0000u; return __uint_as_float(t);
}

// ---------------- CSR build ----------------

__global__ __launch_bounds__(256) void k_count(const int* __restrict__ col,
                                               int* __restrict__ degi, int E) {
    int e = blockIdx.x * 256 + threadIdx.x;
    if (e < E) atomicAdd(&degi[col[e]], 1);
}

__global__ __launch_bounds__(256) void k_scan1(const int* __restrict__ degi,
                                               int* __restrict__ excl,
                                               int* __restrict__ bsum, int n) {
    int i = blockIdx.x * 256 + threadIdx.x;
    int v = (i < n) ? degi[i] : 0;
    int lane = threadIdx.x & 63, w = threadIdx.x >> 6;
    int s = v;
    #pragma unroll
    for (int o = 1; o < 64; o <<= 1) {
        int t = __shfl_up(s, o);
        if (lane >= o) s += t;
    }
    __shared__ int wsum[4];
    if (lane == 63) wsum[w] = s;
    __syncthreads();
    int add = 0;
    for (int ww = 0; ww < w; ww++) add += wsum[ww];
    int incl = s + add;
    if (i < n) excl[i] = incl - v;
    if (threadIdx.x == 255) bsum[blockIdx.x] = incl;
}

__global__ __launch_bounds__(256) void k_scan2(int* __restrict__ bsum, int nb) {
    int i = threadIdx.x;
    int v = (i < nb) ? bsum[i] : 0;
    int lane = i & 63, w = i >> 6;
    int s = v;
    #pragma unroll
    for (int o = 1; o < 64; o <<= 1) {
        int t = __shfl_up(s, o);
        if (lane >= o) s += t;
    }
    __shared__ int wsum[4];
    if (lane == 63) wsum[w] = s;
    __syncthreads();
    int add = 0;
    for (int ww = 0; ww < w; ww++) add += wsum[ww];
    if (i < nb) bsum[i] = (s + add) - v;
}

// rowptr/dis; also sets bucket cursors (bucket = 256 nodes): bcur[b] = rowptr[b*256]
__global__ __launch_bounds__(256) void k_scan3(const int* __restrict__ excl,
                                               const int* __restrict__ bsum,
                                               const int* __restrict__ degi,
                                               int* __restrict__ rowptr,
                                               int* __restrict__ bcur,
                                               float* __restrict__ dis,
                                               int n, int E) {
    int i = blockIdx.x * 256 + threadIdx.x;
    if (i < n) {
        int p = excl[i] + bsum[blockIdx.x];
        rowptr[i] = p;
        if ((i & 255) == 0) bcur[i >> 8] = p;
        int d = degi[i];
        dis[i] = d > 0 ? rsqrtf((float)d) : 0.f;
    }
    if (i == 0) rowptr[n] = E;
}

// Pass A: bin edges into 196 fine buckets (col>>8, 256 nodes each). Per block:
// LDS histogram -> one contiguous reservation per bucket (196 global atomics)
// -> dense appends (each bucket-block chunk is contiguous -> write-combines).
// Replaces the single-pass random 2B scatter (42MB HBM write amp, r14/r16).
__global__ __launch_bounds__(256) void k_binA(const int* __restrict__ row,
                                              const int* __restrict__ col,
                                              int* __restrict__ bcur,
                                              uint* __restrict__ stage, int E) {
    __shared__ uint colbuf[2048];
    __shared__ int hist[196];
    __shared__ int lcur[196];
    int tid = threadIdx.x;
    int base = blockIdx.x * 2048;
    if (tid < 196) hist[tid] = 0;
    __syncthreads();
    #pragma unroll
    for (int i = 0; i < 8; i++) {
        int e = base + i * 256 + tid;
        uint c = 0xFFFFFFFFu;
        if (e < E) {
            c = (uint)col[e];
            atomicAdd(&hist[c >> 8], 1);
        }
        colbuf[i * 256 + tid] = c;
    }
    __syncthreads();
    if (tid < 196 && hist[tid] > 0) lcur[tid] = atomicAdd(&bcur[tid], hist[tid]);
    __syncthreads();
    #pragma unroll
    for (int i = 0; i < 8; i++) {
        int idx = i * 256 + tid;
        uint c = colbuf[idx];
        if (c != 0xFFFFFFFFu) {
            uint r = (uint)row[base + idx];
            int p = atomicAdd(&lcur[c >> 8], 1);
            stage[p] = (c << 16) | r;
        }
    }
}

// Pass B: one block per bucket; slice = exactly this bucket's edges (no
// filter, no re-scan — r15's 16x read-amp mistake fixed). Streams ~4K stage
// entries, places rows via 256 LDS cursors into an 8KB csr16 window.
__global__ __launch_bounds__(256) void k_binB(const uint* __restrict__ stage,
                                              const int* __restrict__ rowptr,
                                              ushort* __restrict__ csr16, int n) {
    __shared__ int cur[256];
    int b = blockIdx.x;
    int lo = b << 8;
    int hi = min(lo + 256, n);
    int gstart = rowptr[lo];
    int gend = rowptr[hi];
    for (int i = threadIdx.x; i < hi - lo; i += 256) cur[i] = rowptr[lo + i];
    __syncthreads();
    for (int idx = gstart + threadIdx.x; idx < gend; idx += 256) {
        uint pk = stage[idx];
        int p = atomicAdd(&cur[(pk >> 16) & 255], 1);
        csr16[p] = (ushort)(pk & 0xffffu);
    }
}

// ---------------- input split: x -> bf16 hi/lo + dis-scaled gather copy ----------------

__global__ __launch_bounds__(256) void k_prepX(const float* __restrict__ x,
                                               const float* __restrict__ dis,
                                               ushort* __restrict__ xh,
                                               ushort* __restrict__ xl,
                                               ushort* __restrict__ xs, int total4) {
    int i = blockIdx.x * 256 + threadIdx.x;
    if (i >= total4) return;
    float4 v = reinterpret_cast<const float4*>(x)[i];
    float dn = dis[i >> 4];                  // node = (i*4)/64
    float vv[4] = {v.x, v.y, v.z, v.w};
    uint hv[2], lv[2], sv[2];
    #pragma unroll
    for (int g = 0; g < 2; g++) {
        float a0 = vv[g * 2], a1 = vv[g * 2 + 1];
        ushort h0 = bf16_bits(a0), l0 = bf16_bits(a0 - bf16_val(a0));
        ushort h1 = bf16_bits(a1), l1 = bf16_bits(a1 - bf16_val(a1));
        hv[g] = (uint)h0 | ((uint)h1 << 16);
        lv[g] = (uint)l0 | ((uint)l1 << 16);
        sv[g] = (uint)bf16_bits(a0 * dn) | ((uint)bf16_bits(a1 * dn) << 16);
    }
    reinterpret_cast<uint2*>(xh)[i] = make_uint2(hv[0], hv[1]);
    reinterpret_cast<uint2*>(xl)[i] = make_uint2(lv[0], lv[1]);
    reinterpret_cast<uint2*>(xs)[i] = make_uint2(sv[0], sv[1]);
}

// ---------------- CSR aggregations (gather, no atomics) ----------------

// agg[i] = dis[i] * sum_e xs[row_e]  (xs pre-scaled by dis[row]).
// TWO nodes per wave (half-wave each, uint = 2 bf16/lane), U=8.
__global__ __launch_bounds__(256) void k_agg64_csr(const ushort* __restrict__ xs,
                                                   const int* __restrict__ rowptr,
                                                   const ushort* __restrict__ csr16,
                                                   const float* __restrict__ dis,
                                                   ushort* __restrict__ agghi,
                                                   ushort* __restrict__ agglo, int n) {
    int node = blockIdx.x * 8 + (threadIdx.x >> 5);
    if (node >= n) return;
    int lane = threadIdx.x & 31;           // half-wave lane: 2 dims per lane
    int s = rowptr[node], t = rowptr[node + 1];
    constexpr int U = 8;
    float2 acc = {0.f, 0.f};
    int p = s;
    for (; p + U <= t; p += U) {
        int rr[U];
        #pragma unroll
        for (int u = 0; u < U; u++) rr[u] = csr16[p + u];
        uint vv[U];
        #pragma unroll
        for (int u = 0; u < U; u++)
            vv[u] = *reinterpret_cast<const uint*>(&xs[(size_t)rr[u] * 64 + lane * 2]);
        #pragma unroll
        for (int u = 0; u < U; u++) {
            acc.x += bfu_lo(vv[u]);
            acc.y += bfu_hi(vv[u]);
        }
    }
    for (; p < t; ++p) {
        uint u = *reinterpret_cast<const uint*>(&xs[(size_t)csr16[p] * 64 + lane * 2]);
        acc.x += bfu_lo(u);
        acc.y += bfu_hi(u);
    }
    float dn = dis[node];
    acc.x *= dn; acc.y *= dn;
    float hx = bf16_val(acc.x), hy = bf16_val(acc.y);
    uint hpack = (uint)bf16_bits(acc.x) | ((uint)bf16_bits(acc.y) << 16);
    uint lpack = (uint)bf16_bits(acc.x - hx) | ((uint)bf16_bits(acc.y - hy) << 16);
    *reinterpret_cast<uint*>(&agghi[(size_t)node * 64 + lane * 2]) = hpack;
    *reinterpret_cast<uint*>(&agglo[(size_t)node * 64 + lane * 2]) = lpack;
}

// Fused x7 + dual dot, wide-granule gather: lane = sub(0..3)*16 + li(0..15);
// each lane loads uint4 (16B) of row csr16[p+sub] -> one instruction fetches
// 4 rows (1KB). Slots combined via shfl_xor(16/32).
__global__ __launch_bounds__(256) void k_agg128_x7dot(
    const ushort* __restrict__ xw,
    const int* __restrict__ rowptr,
    const ushort* __restrict__ csr16,
    const float* __restrict__ dis,
    const float* __restrict__ b2,
    const float* __restrict__ x5,
    const float* __restrict__ wfc2, const float* __restrict__ bfc2,
    const float* __restrict__ wc3,  const float* __restrict__ bc3,
    float* __restrict__ out, float* __restrict__ xw3, int n) {
    int node = blockIdx.x * 4 + (threadIdx.x >> 6);
    if (node >= n) return;
    int lane = threadIdx.x & 63;
    int sub = lane >> 4;          // edge slot 0..3
    int li  = lane & 15;          // dim group: dims li*8 .. li*8+7
    int s = rowptr[node], t = rowptr[node + 1];
    float acc[8] = {};
    int p = s;
    for (; p + 16 <= t; p += 16) {
        int rr[4];
        #pragma unroll
        for (int u = 0; u < 4; u++) rr[u] = csr16[p + u * 4 + sub];
        uint4 v[4];
        #pragma unroll
        for (int u = 0; u < 4; u++)
            v[u] = *reinterpret_cast<const uint4*>(&xw[(size_t)rr[u] * 128 + li * 8]);
        #pragma unroll
        for (int u = 0; u < 4; u++) {
            acc[0] += bfu_lo(v[u].x); acc[1] += bfu_hi(v[u].x);
            acc[2] += bfu_lo(v[u].y); acc[3] += bfu_hi(v[u].y);
            acc[4] += bfu_lo(v[u].z); acc[5] += bfu_hi(v[u].z);
            acc[6] += bfu_lo(v[u].w); acc[7] += bfu_hi(v[u].w);
        }
    }
    for (; p < t; p += 4) {
        int e = p + sub;
        if (e < t) {
            int rr = csr16[e];
            uint4 v = *reinterpret_cast<const uint4*>(&xw[(size_t)rr * 128 + li * 8]);
            acc[0] += bfu_lo(v.x); acc[1] += bfu_hi(v.x);
            acc[2] += bfu_lo(v.y); acc[3] += bfu_hi(v.y);
            acc[4] += bfu_lo(v.z); acc[5] += bfu_hi(v.z);
            acc[6] += bfu_lo(v.w); acc[7] += bfu_hi(v.w);
        }
    }
    #pragma unroll
    for (int j = 0; j < 8; j++) {
        acc[j] += __shfl_xor(acc[j], 16);
        acc[j] += __shfl_xor(acc[j], 32);
    }
    float dn = dis[node];
    float s1 = 0.f, s2 = 0.f;
    if (sub == 0) {
        #pragma unroll
        for (int j = 0; j < 8; j++) {
            int d = li * 8 + j;
            float x7 = x5[(size_t)node * 128 + d] + fmaxf(dn * acc[j] + b2[d], 0.f);
            s1 += x7 * wfc2[d];
            s2 += x7 * wc3[d];
        }
    }
    #pragma unroll
    for (int o = 32; o > 0; o >>= 1) {
        s1 += __shfl_down(s1, o);
        s2 += __shfl_down(s2, o);
    }
    if (lane == 0) {
        out[node] = s1 + bfc2[0] + bc3[0];
        xw3[node] = s2 * dn;                   // pre-scale for agg1
    }
}

__global__ __launch_bounds__(256) void k_agg1_csr(const float* __restrict__ sv,
                                                  const int* __restrict__ rowptr,
                                                  const ushort* __restrict__ csr16,
                                                  const float* __restrict__ dis,
                                                  float* __restrict__ out, int n) {
    int i = blockIdx.x * 256 + threadIdx.x;
    if (i >= n) return;
    int s = rowptr[i], t = rowptr[i + 1];
    float a = 0.f;
    #pragma unroll 4
    for (int p = s; p < t; ++p) a += sv[csr16[p]];
    out[i] += dis[i] * a;
}

// ---------------- weight fragment packing (single merged launch) ----------------
__global__ __launch_bounds__(256) void k_prepW(const float* __restrict__ w0,
                                               const float* __restrict__ w1,
                                               const float* __restrict__ wf1,
                                               const float* __restrict__ wf2,
                                               ushort* __restrict__ W0f,
                                               ushort* __restrict__ W1f,
                                               ushort* __restrict__ Bf) {
    int id = blockIdx.x * 256 + threadIdx.x;   // 8192 + 16384 = 24576
    if (id < 8192) {
        int mat = id >> 12;
        int rem = id & 4095;                   // arr*2048 + k0i*1024 + nt*64 + lane
        int lane = rem & 63;
        int nt = (rem >> 6) & 15;
        int k0i = (rem >> 10) & 1;
        int arr = rem >> 11;
        const float* w = mat ? w1 : w0;
        ushort* dst = mat ? W1f : W0f;
        int n = nt * 16 + (lane & 15);
        int kb = k0i * 32 + (lane >> 4) * 8;
        ushort o[8];
        #pragma unroll
        for (int j = 0; j < 8; j++) {
            float v = w[(size_t)(kb + j) * 256 + n];
            o[j] = arr ? bf16_bits(v - bf16_val(v)) : bf16_bits(v);
        }
        *reinterpret_cast<int4*>(&dst[(size_t)rem * 8]) = *reinterpret_cast<const int4*>(o);
    } else if (id < 24576) {
        int rem = id - 8192;                   // 16*16*64
        int lane = rem & 63;
        int nt   = (rem >> 6) & 15;
        int k0i  = (rem >> 10) & 15;
        int n = nt * 16 + (lane & 15);
        int kbase = k0i * 32 + (lane >> 4) * 8;
        ushort outv[8];
        #pragma unroll
        for (int j = 0; j < 8; j++) {
            int k = kbase + j;
            float v = (n < 128) ? wf1[(size_t)k * 128 + n]
                                : wf2[(size_t)k * 128 + (n - 128)];
            outv[j] = bf16_bits(v);
        }
        *reinterpret_cast<int4*>(&Bf[(size_t)rem * 8]) = *reinterpret_cast<const int4*>(outv);
    }
}

// ---------------- MFMA GEMMs ----------------

// K=64 dual-layer MFMA GEMM (blockIdx.y = layer): 3-term split inputs.
__global__ __launch_bounds__(256) void k_mm64(
    const ushort* __restrict__ xh, const ushort* __restrict__ xl,
    const ushort* __restrict__ ah_, const ushort* __restrict__ al_,
    const ushort* __restrict__ W0f, const ushort* __restrict__ W1f,
    const float* __restrict__ b0, const float* __restrict__ b1,
    ushort* __restrict__ Af, int M) {
    const int layer = blockIdx.y;
    const ushort* Ah = layer ? ah_ : xh;
    const ushort* Al = layer ? al_ : xl;
    const ushort* Wf = layer ? W1f : W0f;
    const float* bias = layer ? b1 : b0;
    const int colbase = layer * 256;

    const int t = threadIdx.x;
    const int lane = t & 63;
    const int wv = t >> 6;
    const int m0 = blockIdx.x * 64;
    const int ln15 = lane & 15;
    const int quad = lane >> 4;

    f32x4 acc[4][4] = {};

    #pragma unroll
    for (int k0i = 0; k0i < 2; k0i++) {
        short8 bh[4], bl[4];
        #pragma unroll
        for (int nt4 = 0; nt4 < 4; nt4++) {
            const ushort* pw = Wf + ((size_t)k0i * 16 + wv * 4 + nt4) * 512 + (size_t)lane * 8;
            bh[nt4] = *reinterpret_cast<const short8*>(pw);
            bl[nt4] = *reinterpret_cast<const short8*>(pw + 16384);   // arr=1 offset
        }
        #pragma unroll
        for (int mt = 0; mt < 4; mt++) {
            int gm = m0 + mt * 16 + ln15;
            int gmc = gm < M - 1 ? gm : M - 1;   // clamp: avoid OOB reads on tail rows
            size_t ia = (size_t)gmc * 64 + k0i * 32 + quad * 8;
            short8 ah = *reinterpret_cast<const short8*>(&Ah[ia]);
            short8 al = *reinterpret_cast<const short8*>(&Al[ia]);
            #pragma unroll
            for (int nt4 = 0; nt4 < 4; nt4++) {
                acc[mt][nt4] = __builtin_amdgcn_mfma_f32_16x16x32_bf16(ah, bh[nt4], acc[mt][nt4], 0, 0, 0);
                acc[mt][nt4] = __builtin_amdgcn_mfma_f32_16x16x32_bf16(ah, bl[nt4], acc[mt][nt4], 0, 0, 0);
                acc[mt][nt4] = __builtin_amdgcn_mfma_f32_16x16x32_bf16(al, bh[nt4], acc[mt][nt4], 0, 0, 0);
            }
        }
    }

    // epilogue: C layout col=lane&15, row=quad*4+r -> x3f fragment scatter (hi only)
    #pragma unroll
    for (int mt = 0; mt < 4; mt++) {
        #pragma unroll
        for (int nt4 = 0; nt4 < 4; nt4++) {
            int gn = wv * 64 + nt4 * 16 + ln15;      // local col 0..255
            int gcol = gn + colbase;                 // x3 col 0..511
            int k0f = gcol >> 5, qf = (gcol >> 3) & 3, j = gcol & 7;
            #pragma unroll
            for (int r = 0; r < 4; r++) {
                int gm = m0 + mt * 16 + quad * 4 + r;
                float v = fmaxf(acc[mt][nt4][r] + bias[gn], 0.f);
                size_t base = (((size_t)(gm >> 4)) * 16 + k0f) * 512 + (size_t)(qf * 16 + (gm & 15)) * 8 + j;
                Af[base] = bf16_bits(v);
            }
        }
    }
}

// LDS-free pure-bf16 MFMA dual GEMM, 32-row blocks, A and B register
// double-buffered.
__global__ __launch_bounds__(256) void k_gemm2_mfma(
    const ushort* __restrict__ Af, const ushort* __restrict__ Bf,
    const float* __restrict__ bias1, const float* __restrict__ dis,
    float* __restrict__ C1, ushort* __restrict__ C2, int M) {
    const int t = threadIdx.x;
    const int lane = t & 63;
    const int wv = t >> 6;
    const int mt0 = blockIdx.x * 2;          // two 16-row tiles per block
    const int ln15 = lane & 15;
    const int quad = lane >> 4;

    f32x4 acc[2][4] = {};

    const ushort* aPtr = Af + ((size_t)mt0 * 16) * 512 + (size_t)lane * 8;
    const ushort* bPtr = Bf + ((size_t)wv * 4) * 512 + (size_t)lane * 8;

    short8 aC[2], bC[4];
    #pragma unroll
    for (int mt = 0; mt < 2; mt++)
        aC[mt] = *reinterpret_cast<const short8*>(aPtr + (size_t)mt * 16 * 512);
    #pragma unroll
    for (int nt = 0; nt < 4; nt++)
        bC[nt] = *reinterpret_cast<const short8*>(bPtr + (size_t)nt * 512);

    for (int k0i = 0; k0i < 16; k0i++) {
        short8 aN[2], bN[4];
        if (k0i < 15) {
            #pragma unroll
            for (int mt = 0; mt < 2; mt++)
                aN[mt] = *reinterpret_cast<const short8*>(aPtr + ((size_t)mt * 16 + k0i + 1) * 512);
            #pragma unroll
            for (int nt = 0; nt < 4; nt++)
                bN[nt] = *reinterpret_cast<const short8*>(bPtr + ((size_t)(k0i + 1) * 16 + nt) * 512);
        }
        #pragma unroll
        for (int mt = 0; mt < 2; mt++)
            #pragma unroll
            for (int nt = 0; nt < 4; nt++)
                acc[mt][nt] = __builtin_amdgcn_mfma_f32_16x16x32_bf16(aC[mt], bC[nt], acc[mt][nt], 0, 0, 0);
        if (k0i < 15) {
            #pragma unroll
            for (int mt = 0; mt < 2; mt++) aC[mt] = aN[mt];
            #pragma unroll
            for (int nt = 0; nt < 4; nt++) bC[nt] = bN[nt];
        }
    }

    #pragma unroll
    for (int mt = 0; mt < 2; mt++) {
        float dn[4];
        #pragma unroll
        for (int r = 0; r < 4; r++) {
            int gm = (mt0 + mt) * 16 + quad * 4 + r;
            dn[r] = (gm < M) ? dis[gm] : 0.f;
        }
        #pragma unroll
        for (int nt = 0; nt < 4; nt++) {
            int gn = wv * 64 + nt * 16 + ln15;   // 0..255
            #pragma unroll
            for (int r = 0; r < 4; r++) {
                int gm = (mt0 + mt) * 16 + quad * 4 + r;
                if (gm >= M) continue;
                float v = acc[mt][nt][r];
                if (gn < 128) {
                    C1[(size_t)gm * 128 + gn] = fmaxf(v + bias1[gn], 0.f);
                } else {
                    C2[(size_t)gm * 128 + (gn - 128)] = bf16_bits(v * dn[r]);
                }
            }
        }
    }
}

extern "C" void kernel_launch(void* const* d_in, const int* in_sizes, int n_in,
                              void* d_out, int out_size, void* d_ws, size_t ws_size,
                              hipStream_t stream) {
    const float* x       = (const float*)d_in[0];
    const int*   ei      = (const int*)d_in[1];
    const float* w_fc    = (const float*)d_in[2];
    const float* b_fc    = (const float*)d_in[3];
    const float* w_conv1 = (const float*)d_in[4];
    const float* b_conv1 = (const float*)d_in[5];
    const float* w_fc1   = (const float*)d_in[6];
    const float* b_fc1   = (const float*)d_in[7];
    const float* w_conv2 = (const float*)d_in[8];
    const float* b_conv2 = (const float*)d_in[9];
    const float* w_fc2   = (const float*)d_in[10];
    const float* b_fc2   = (const float*)d_in[11];
    const float* w_conv3 = (const float*)d_in[12];
    const float* b_conv3 = (const float*)d_in[13];

    const int N = in_sizes[0] / 64;       // 50000
    const int E = in_sizes[1] / 2;        // 800000
    const int* row = ei;
    const int* col = ei + E;

    const int nb = (N + 255) / 256;       // 196 (scan blocks == buckets)
    const int nblk = (N + 63) / 64;       // 782  (64-row blocks, mm64)
    const int nblk2 = (N + 31) / 32;      // 1563 (32-row blocks, gemm2)
    const int Mt = nblk * 4;              // 3128 row-tiles of 16

    // workspace layout. alloc() takes 4-BYTE units (chunks padded to 16B).
    char* p = (char*)d_ws;
    auto alloc = [&](size_t elems) {
        void* q = p; p += ((elems + 3) & ~(size_t)3) * 4; return q;
    };
    int*    degi    = (int*)   alloc(N);
    int*    excl    = (int*)   alloc(N);
    int*    bsum    = (int*)   alloc(256);
    int*    rowptr  = (int*)   alloc(N + 4);
    int*    bcur    = (int*)   alloc(200);                 // 196 bucket cursors
    uint*   stage   = (uint*)  alloc(E);                   // packed (col<<16|row)
    ushort* csr16   = (ushort*)alloc((size_t)E / 2);       // 2B row index per edge
    float*  dis     = (float*) alloc(N);
    ushort* xh      = (ushort*)alloc((size_t)N * 32);      // N*64 bf16 = N*32 words
    ushort* xl      = (ushort*)alloc((size_t)N * 32);
    ushort* xs      = (ushort*)alloc((size_t)N * 32);      // dis-scaled gather copy
    ushort* agghi   = (ushort*)alloc((size_t)N * 32);
    ushort* agglo   = (ushort*)alloc((size_t)N * 32);
    ushort* x3f     = (ushort*)alloc((size_t)Mt * 4096);   // hi only: Mt*16*64*8 ushorts
    ushort* Bf      = (ushort*)alloc(65536);               // single bf16
    ushort* W0f     = (ushort*)alloc(16384);
    ushort* W1f     = (ushort*)alloc(16384);
    float*  x5      = (float*) alloc((size_t)N * 128);
    ushort* xw2     = (ushort*)alloc((size_t)N * 64);      // N*128 bf16
    float*  xw3     = (float*) alloc(N);

    float* out = (float*)d_out;

    // ---- CSR build ----
    hipMemsetAsync(degi, 0, (size_t)N * sizeof(int), stream);
    k_count<<<(E + 255) / 256, 256, 0, stream>>>(col, degi, E);
    k_scan1<<<nb, 256, 0, stream>>>(degi, excl, bsum, N);
    k_scan2<<<1, 256, 0, stream>>>(bsum, nb);
    k_scan3<<<nb, 256, 0, stream>>>(excl, bsum, degi, rowptr, bcur, dis, N, E);
    k_binA<<<(E + 2047) / 2048, 256, 0, stream>>>(row, col, bcur, stage, E);
    k_binB<<<nb, 256, 0, stream>>>(stage, rowptr, csr16, N);

    // input split (+dis-scaled copy) + weight fragment packing
    k_prepX<<<(N * 16 + 255) / 256, 256, 0, stream>>>(x, dis, xh, xl, xs, N * 16);
    k_prepW<<<24576 / 256, 256, 0, stream>>>(w_fc, w_conv1, w_fc1, w_conv2,
                                             W0f, W1f, Bf);

    // conv1 propagate: agg = dis[col] * sum xs[row], 2 nodes/wave
    k_agg64_csr<<<(N + 7) / 8, 256, 0, stream>>>(xs, rowptr, csr16, dis, agghi, agglo, N);

    // x1/x2 layers via MFMA -> x3f fragments (single bf16)
    k_mm64<<<dim3(nblk, 2), 256, 0, stream>>>(xh, xl, agghi, agglo, W0f, W1f,
                                              b_fc, b_conv1, x3f, N);

    // x5 = relu(x3 @ w_fc1 + b_fc1) ; xw2 = dis * (x3 @ w_conv2) (bf16 MFMA)
    k_gemm2_mfma<<<nblk2, 256, 0, stream>>>(x3f, Bf, b_fc1, dis, x5, xw2, N);

    // x7 in registers (wide-granule gather); fused dual dot -> out, xw3
    k_agg128_x7dot<<<(N + 3) / 4, 256, 0, stream>>>(
        xw2, rowptr, csr16, dis, b_conv2, x5,
        w_fc2, b_fc2, w_conv3, b_conv3, out, xw3, N);

    // out += dis[i] * sum xw3[row]
    k_agg1_csr<<<(N + 255) / 256, 256, 0, stream>>>(xw3, rowptr, csr16, dis, out, N);
}

// Round 18
// 278.238 us; speedup vs baseline: 1.6270x; 1.1148x over previous
//
#include <hip/hip_runtime.h>
#include <hip/hip_bf16.h>

typedef __attribute__((ext_vector_type(8))) short short8;
typedef __attribute__((ext_vector_type(4))) float f32x4;

__device__ __forceinline__ ushort bf16_bits(float v) {
    __hip_bfloat16 h = __float2bfloat16(v);
    return *reinterpret_cast<ushort*>(&h);
}
__device__ __forceinline__ float bf16_val(float v) {
    __hip_bfloat16 h = __float2bfloat16(v);
    return __bfloat162float(h);
}
__device__ __forceinline__ float bfu_lo(uint u) {
    uint t = u << 16; return __uint_as_float(t);
}
__device__ __forceinline__ float bfu_hi(uint u) {
    uint t = u & 0xffff0000u; return __uint_as_float(t);
}

// ---------------- CSR build (count-free: degrees computed in binB) ----------------

// Bucket-count: LDS histogram of col>>8 per block, one global atomic per
// non-empty bucket per block. Replaces k_count's 800K random atomics.
__global__ __launch_bounds__(256) void k_bcount(const int* __restrict__ col,
                                                int* __restrict__ bcnt, int E) {
    __shared__ int hist[196];
    int tid = threadIdx.x;
    int base = blockIdx.x * 2048;
    if (tid < 196) hist[tid] = 0;
    __syncthreads();
    #pragma unroll
    for (int i = 0; i < 8; i++) {
        int e = base + i * 256 + tid;
        if (e < E) atomicAdd(&hist[col[e] >> 8], 1);
    }
    __syncthreads();
    if (tid < 196 && hist[tid] > 0) atomicAdd(&bcnt[tid], hist[tid]);
}

// One-block exclusive scan of the 196 bucket counts -> bbase, bcur.
__global__ __launch_bounds__(256) void k_bscan(const int* __restrict__ bcnt,
                                               int* __restrict__ bbase,
                                               int* __restrict__ bcur, int E) {
    int i = threadIdx.x;
    int v = (i < 196) ? bcnt[i] : 0;
    int lane = i & 63, w = i >> 6;
    int s = v;
    #pragma unroll
    for (int o = 1; o < 64; o <<= 1) {
        int t = __shfl_up(s, o);
        if (lane >= o) s += t;
    }
    __shared__ int wsum[4];
    if (lane == 63) wsum[w] = s;
    __syncthreads();
    int add = 0;
    for (int ww = 0; ww < w; ww++) add += wsum[ww];
    int excl = s + add - v;
    if (i < 196) {
        bbase[i] = excl;
        bcur[i] = excl;
    }
    if (i == 195) bbase[196] = excl + v;   // == E
}

// Pass A: bin edges into 196 fine buckets (col>>8). Per block: LDS histogram
// -> contiguous reservation per bucket -> dense appends (write-combines).
__global__ __launch_bounds__(256) void k_binA(const int* __restrict__ row,
                                              const int* __restrict__ col,
                                              int* __restrict__ bcur,
                                              uint* __restrict__ stage, int E) {
    __shared__ uint colbuf[2048];
    __shared__ int hist[196];
    __shared__ int lcur[196];
    int tid = threadIdx.x;
    int base = blockIdx.x * 2048;
    if (tid < 196) hist[tid] = 0;
    __syncthreads();
    #pragma unroll
    for (int i = 0; i < 8; i++) {
        int e = base + i * 256 + tid;
        uint c = 0xFFFFFFFFu;
        if (e < E) {
            c = (uint)col[e];
            atomicAdd(&hist[c >> 8], 1);
        }
        colbuf[i * 256 + tid] = c;
    }
    __syncthreads();
    if (tid < 196 && hist[tid] > 0) lcur[tid] = atomicAdd(&bcur[tid], hist[tid]);
    __syncthreads();
    #pragma unroll
    for (int i = 0; i < 8; i++) {
        int idx = i * 256 + tid;
        uint c = colbuf[idx];
        if (c != 0xFFFFFFFFu) {
            uint r = (uint)row[base + idx];
            int p = atomicAdd(&lcur[c >> 8], 1);
            stage[p] = (c << 16) | r;
        }
    }
}

// Pass B: one block per bucket. Pass 1 over the (L2-hot) slice: per-node LDS
// degree count -> 256-wide LDS scan -> rowptr + dis for this bucket's nodes.
// Pass 2: place csr16 via LDS cursors. Eliminates k_count + k_scan1/2/3.
__global__ __launch_bounds__(256) void k_binB(const uint* __restrict__ stage,
                                              const int* __restrict__ bbase,
                                              int* __restrict__ rowptr,
                                              float* __restrict__ dis,
                                              ushort* __restrict__ csr16,
                                              int n, int E) {
    __shared__ int cnt[256];
    __shared__ int cur[256];
    __shared__ int wsum[4];
    int b = blockIdx.x;
    int lo = b << 8;
    int tid = threadIdx.x;
    int gstart = bbase[b], gend = bbase[b + 1];
    cnt[tid] = 0;
    __syncthreads();
    for (int idx = gstart + tid; idx < gend; idx += 256)
        atomicAdd(&cnt[(stage[idx] >> 16) & 255], 1);
    __syncthreads();
    int v = cnt[tid];
    int lane = tid & 63, w = tid >> 6;
    int s = v;
    #pragma unroll
    for (int o = 1; o < 64; o <<= 1) {
        int t = __shfl_up(s, o);
        if (lane >= o) s += t;
    }
    if (lane == 63) wsum[w] = s;
    __syncthreads();
    int add = 0;
    for (int ww = 0; ww < w; ww++) add += wsum[ww];
    int excl = s + add - v + gstart;
    int node = lo + tid;
    if (node < n) {
        rowptr[node] = excl;
        dis[node] = v > 0 ? rsqrtf((float)v) : 0.f;
    }
    cur[tid] = excl;
    if (node == n - 1 || (tid == 255 && node < n)) { /* nothing */ }
    if (tid == 0 && b == gridDim.x - 1) rowptr[n] = E;
    __syncthreads();
    for (int idx = gstart + tid; idx < gend; idx += 256) {
        uint pk = stage[idx];
        int p = atomicAdd(&cur[(pk >> 16) & 255], 1);
        csr16[p] = (ushort)(pk & 0xffffu);
    }
}

// ---------------- input split: x -> bf16 hi/lo + dis-scaled gather copy ----------------

__global__ __launch_bounds__(256) void k_prepX(const float* __restrict__ x,
                                               const float* __restrict__ dis,
                                               ushort* __restrict__ xh,
                                               ushort* __restrict__ xl,
                                               ushort* __restrict__ xs, int total4) {
    int i = blockIdx.x * 256 + threadIdx.x;
    if (i >= total4) return;
    float4 v = reinterpret_cast<const float4*>(x)[i];
    float dn = dis[i >> 4];                  // node = (i*4)/64
    float vv[4] = {v.x, v.y, v.z, v.w};
    uint hv[2], lv[2], sv[2];
    #pragma unroll
    for (int g = 0; g < 2; g++) {
        float a0 = vv[g * 2], a1 = vv[g * 2 + 1];
        ushort h0 = bf16_bits(a0), l0 = bf16_bits(a0 - bf16_val(a0));
        ushort h1 = bf16_bits(a1), l1 = bf16_bits(a1 - bf16_val(a1));
        hv[g] = (uint)h0 | ((uint)h1 << 16);
        lv[g] = (uint)l0 | ((uint)l1 << 16);
        sv[g] = (uint)bf16_bits(a0 * dn) | ((uint)bf16_bits(a1 * dn) << 16);
    }
    reinterpret_cast<uint2*>(xh)[i] = make_uint2(hv[0], hv[1]);
    reinterpret_cast<uint2*>(xl)[i] = make_uint2(lv[0], lv[1]);
    reinterpret_cast<uint2*>(xs)[i] = make_uint2(sv[0], sv[1]);
}

// ---------------- CSR aggregations (gather, no atomics) ----------------

// agg[i] = dis[i] * sum_e xs[row_e], wide-granule: lane = sub(0..7)*8+li(0..7);
// each lane loads uint4 (16B) of row csr16[p+sub] -> 8 rows (1KB) per
// instruction. Slots combined via shfl_xor(8/16/32); lanes 0..7 write the
// 128B output row as coalesced uint4.
__global__ __launch_bounds__(256) void k_agg64_csr(const ushort* __restrict__ xs,
                                                   const int* __restrict__ rowptr,
                                                   const ushort* __restrict__ csr16,
                                                   const float* __restrict__ dis,
                                                   ushort* __restrict__ agghi,
                                                   ushort* __restrict__ agglo, int n) {
    int node = blockIdx.x * 4 + (threadIdx.x >> 6);
    if (node >= n) return;
    int lane = threadIdx.x & 63;
    int sub = lane >> 3;          // edge slot 0..7
    int li  = lane & 7;           // dim group: dims li*8 .. li*8+7
    int s = rowptr[node], t = rowptr[node + 1];
    float acc[8] = {};
    int p = s;
    for (; p + 16 <= t; p += 16) {
        int rr[2];
        #pragma unroll
        for (int u = 0; u < 2; u++) rr[u] = csr16[p + u * 8 + sub];
        uint4 v[2];
        #pragma unroll
        for (int u = 0; u < 2; u++)
            v[u] = *reinterpret_cast<const uint4*>(&xs[(size_t)rr[u] * 64 + li * 8]);
        #pragma unroll
        for (int u = 0; u < 2; u++) {
            acc[0] += bfu_lo(v[u].x); acc[1] += bfu_hi(v[u].x);
            acc[2] += bfu_lo(v[u].y); acc[3] += bfu_hi(v[u].y);
            acc[4] += bfu_lo(v[u].z); acc[5] += bfu_hi(v[u].z);
            acc[6] += bfu_lo(v[u].w); acc[7] += bfu_hi(v[u].w);
        }
    }
    for (; p < t; p += 8) {
        int e = p + sub;
        if (e < t) {
            int rr = csr16[e];
            uint4 v = *reinterpret_cast<const uint4*>(&xs[(size_t)rr * 64 + li * 8]);
            acc[0] += bfu_lo(v.x); acc[1] += bfu_hi(v.x);
            acc[2] += bfu_lo(v.y); acc[3] += bfu_hi(v.y);
            acc[4] += bfu_lo(v.z); acc[5] += bfu_hi(v.z);
            acc[6] += bfu_lo(v.w); acc[7] += bfu_hi(v.w);
        }
    }
    #pragma unroll
    for (int j = 0; j < 8; j++) {
        acc[j] += __shfl_xor(acc[j], 8);
        acc[j] += __shfl_xor(acc[j], 16);
        acc[j] += __shfl_xor(acc[j], 32);
    }
    if (sub == 0) {
        float dn = dis[node];
        uint hp[4], lp[4];
        #pragma unroll
        for (int g = 0; g < 4; g++) {
            float a0 = acc[g * 2] * dn, a1 = acc[g * 2 + 1] * dn;
            ushort h0 = bf16_bits(a0), h1 = bf16_bits(a1);
            ushort l0 = bf16_bits(a0 - bf16_val(a0)), l1 = bf16_bits(a1 - bf16_val(a1));
            hp[g] = (uint)h0 | ((uint)h1 << 16);
            lp[g] = (uint)l0 | ((uint)l1 << 16);
        }
        *reinterpret_cast<uint4*>(&agghi[(size_t)node * 64 + li * 8]) =
            make_uint4(hp[0], hp[1], hp[2], hp[3]);
        *reinterpret_cast<uint4*>(&agglo[(size_t)node * 64 + li * 8]) =
            make_uint4(lp[0], lp[1], lp[2], lp[3]);
    }
}

// Fused x7 + dual dot, wide-granule gather: lane = sub(0..3)*16 + li(0..15);
// each lane loads uint4 (16B) of row csr16[p+sub] -> 4 rows (1KB) per
// instruction. Slots combined via shfl_xor(16/32).
__global__ __launch_bounds__(256) void k_agg128_x7dot(
    const ushort* __restrict__ xw,
    const int* __restrict__ rowptr,
    const ushort* __restrict__ csr16,
    const float* __restrict__ dis,
    const float* __restrict__ b2,
    const float* __restrict__ x5,
    const float* __restrict__ wfc2, const float* __restrict__ bfc2,
    const float* __restrict__ wc3,  const float* __restrict__ bc3,
    float* __restrict__ out, float* __restrict__ xw3, int n) {
    int node = blockIdx.x * 4 + (threadIdx.x >> 6);
    if (node >= n) return;
    int lane = threadIdx.x & 63;
    int sub = lane >> 4;          // edge slot 0..3
    int li  = lane & 15;          // dim group: dims li*8 .. li*8+7
    int s = rowptr[node], t = rowptr[node + 1];
    float acc[8] = {};
    int p = s;
    for (; p + 16 <= t; p += 16) {
        int rr[4];
        #pragma unroll
        for (int u = 0; u < 4; u++) rr[u] = csr16[p + u * 4 + sub];
        uint4 v[4];
        #pragma unroll
        for (int u = 0; u < 4; u++)
            v[u] = *reinterpret_cast<const uint4*>(&xw[(size_t)rr[u] * 128 + li * 8]);
        #pragma unroll
        for (int u = 0; u < 4; u++) {
            acc[0] += bfu_lo(v[u].x); acc[1] += bfu_hi(v[u].x);
            acc[2] += bfu_lo(v[u].y); acc[3] += bfu_hi(v[u].y);
            acc[4] += bfu_lo(v[u].z); acc[5] += bfu_hi(v[u].z);
            acc[6] += bfu_lo(v[u].w); acc[7] += bfu_hi(v[u].w);
        }
    }
    for (; p < t; p += 4) {
        int e = p + sub;
        if (e < t) {
            int rr = csr16[e];
            uint4 v = *reinterpret_cast<const uint4*>(&xw[(size_t)rr * 128 + li * 8]);
            acc[0] += bfu_lo(v.x); acc[1] += bfu_hi(v.x);
            acc[2] += bfu_lo(v.y); acc[3] += bfu_hi(v.y);
            acc[4] += bfu_lo(v.z); acc[5] += bfu_hi(v.z);
            acc[6] += bfu_lo(v.w); acc[7] += bfu_hi(v.w);
        }
    }
    #pragma unroll
    for (int j = 0; j < 8; j++) {
        acc[j] += __shfl_xor(acc[j], 16);
        acc[j] += __shfl_xor(acc[j], 32);
    }
    float dn = dis[node];
    float s1 = 0.f, s2 = 0.f;
    if (sub == 0) {
        #pragma unroll
        for (int j = 0; j < 8; j++) {
            int d = li * 8 + j;
            float x7 = x5[(size_t)node * 128 + d] + fmaxf(dn * acc[j] + b2[d], 0.f);
            s1 += x7 * wfc2[d];
            s2 += x7 * wc3[d];
        }
    }
    #pragma unroll
    for (int o = 32; o > 0; o >>= 1) {
        s1 += __shfl_down(s1, o);
        s2 += __shfl_down(s2, o);
    }
    if (lane == 0) {
        out[node] = s1 + bfc2[0] + bc3[0];
        xw3[node] = s2 * dn;                   // pre-scale for agg1
    }
}

__global__ __launch_bounds__(256) void k_agg1_csr(const float* __restrict__ sv,
                                                  const int* __restrict__ rowptr,
                                                  const ushort* __restrict__ csr16,
                                                  const float* __restrict__ dis,
                                                  float* __restrict__ out, int n) {
    int i = blockIdx.x * 256 + threadIdx.x;
    if (i >= n) return;
    int s = rowptr[i], t = rowptr[i + 1];
    float a = 0.f;
    #pragma unroll 4
    for (int p = s; p < t; ++p) a += sv[csr16[p]];
    out[i] += dis[i] * a;
}

// ---------------- weight fragment packing (single merged launch) ----------------
__global__ __launch_bounds__(256) void k_prepW(const float* __restrict__ w0,
                                               const float* __restrict__ w1,
                                               const float* __restrict__ wf1,
                                               const float* __restrict__ wf2,
                                               ushort* __restrict__ W0f,
                                               ushort* __restrict__ W1f,
                                               ushort* __restrict__ Bf) {
    int id = blockIdx.x * 256 + threadIdx.x;   // 8192 + 16384 = 24576
    if (id < 8192) {
        int mat = id >> 12;
        int rem = id & 4095;                   // arr*2048 + k0i*1024 + nt*64 + lane
        int lane = rem & 63;
        int nt = (rem >> 6) & 15;
        int k0i = (rem >> 10) & 1;
        int arr = rem >> 11;
        const float* w = mat ? w1 : w0;
        ushort* dst = mat ? W1f : W0f;
        int n = nt * 16 + (lane & 15);
        int kb = k0i * 32 + (lane >> 4) * 8;
        ushort o[8];
        #pragma unroll
        for (int j = 0; j < 8; j++) {
            float v = w[(size_t)(kb + j) * 256 + n];
            o[j] = arr ? bf16_bits(v - bf16_val(v)) : bf16_bits(v);
        }
        *reinterpret_cast<int4*>(&dst[(size_t)rem * 8]) = *reinterpret_cast<const int4*>(o);
    } else if (id < 24576) {
        int rem = id - 8192;                   // 16*16*64
        int lane = rem & 63;
        int nt   = (rem >> 6) & 15;
        int k0i  = (rem >> 10) & 15;
        int n = nt * 16 + (lane & 15);
        int kbase = k0i * 32 + (lane >> 4) * 8;
        ushort outv[8];
        #pragma unroll
        for (int j = 0; j < 8; j++) {
            int k = kbase + j;
            float v = (n < 128) ? wf1[(size_t)k * 128 + n]
                                : wf2[(size_t)k * 128 + (n - 128)];
            outv[j] = bf16_bits(v);
        }
        *reinterpret_cast<int4*>(&Bf[(size_t)rem * 8]) = *reinterpret_cast<const int4*>(outv);
    }
}

// ---------------- MFMA GEMMs ----------------

// K=64 dual-layer MFMA GEMM (blockIdx.y = layer): 3-term split inputs.
__global__ __launch_bounds__(256) void k_mm64(
    const ushort* __restrict__ xh, const ushort* __restrict__ xl,
    const ushort* __restrict__ ah_, const ushort* __restrict__ al_,
    const ushort* __restrict__ W0f, const ushort* __restrict__ W1f,
    const float* __restrict__ b0, const float* __restrict__ b1,
    ushort* __restrict__ Af, int M) {
    const int layer = blockIdx.y;
    const ushort* Ah = layer ? ah_ : xh;
    const ushort* Al = layer ? al_ : xl;
    const ushort* Wf = layer ? W1f : W0f;
    const float* bias = layer ? b1 : b0;
    const int colbase = layer * 256;

    const int t = threadIdx.x;
    const int lane = t & 63;
    const int wv = t >> 6;
    const int m0 = blockIdx.x * 64;
    const int ln15 = lane & 15;
    const int quad = lane >> 4;

    f32x4 acc[4][4] = {};

    #pragma unroll
    for (int k0i = 0; k0i < 2; k0i++) {
        short8 bh[4], bl[4];
        #pragma unroll
        for (int nt4 = 0; nt4 < 4; nt4++) {
            const ushort* pw = Wf + ((size_t)k0i * 16 + wv * 4 + nt4) * 512 + (size_t)lane * 8;
            bh[nt4] = *reinterpret_cast<const short8*>(pw);
            bl[nt4] = *reinterpret_cast<const short8*>(pw + 16384);   // arr=1 offset
        }
        #pragma unroll
        for (int mt = 0; mt < 4; mt++) {
            int gm = m0 + mt * 16 + ln15;
            int gmc = gm < M - 1 ? gm : M - 1;   // clamp: avoid OOB reads on tail rows
            size_t ia = (size_t)gmc * 64 + k0i * 32 + quad * 8;
            short8 ah = *reinterpret_cast<const short8*>(&Ah[ia]);
            short8 al = *reinterpret_cast<const short8*>(&Al[ia]);
            #pragma unroll
            for (int nt4 = 0; nt4 < 4; nt4++) {
                acc[mt][nt4] = __builtin_amdgcn_mfma_f32_16x16x32_bf16(ah, bh[nt4], acc[mt][nt4], 0, 0, 0);
                acc[mt][nt4] = __builtin_amdgcn_mfma_f32_16x16x32_bf16(ah, bl[nt4], acc[mt][nt4], 0, 0, 0);
                acc[mt][nt4] = __builtin_amdgcn_mfma_f32_16x16x32_bf16(al, bh[nt4], acc[mt][nt4], 0, 0, 0);
            }
        }
    }

    // epilogue: C layout col=lane&15, row=quad*4+r -> x3f fragment scatter (hi only)
    #pragma unroll
    for (int mt = 0; mt < 4; mt++) {
        #pragma unroll
        for (int nt4 = 0; nt4 < 4; nt4++) {
            int gn = wv * 64 + nt4 * 16 + ln15;      // local col 0..255
            int gcol = gn + colbase;                 // x3 col 0..511
            int k0f = gcol >> 5, qf = (gcol >> 3) & 3, j = gcol & 7;
            #pragma unroll
            for (int r = 0; r < 4; r++) {
                int gm = m0 + mt * 16 + quad * 4 + r;
                float v = fmaxf(acc[mt][nt4][r] + bias[gn], 0.f);
                size_t base = (((size_t)(gm >> 4)) * 16 + k0f) * 512 + (size_t)(qf * 16 + (gm & 15)) * 8 + j;
                Af[base] = bf16_bits(v);
            }
        }
    }
}

// LDS-free pure-bf16 MFMA dual GEMM, 32-row blocks, A and B register
// double-buffered.
__global__ __launch_bounds__(256) void k_gemm2_mfma(
    const ushort* __restrict__ Af, const ushort* __restrict__ Bf,
    const float* __restrict__ bias1, const float* __restrict__ dis,
    float* __restrict__ C1, ushort* __restrict__ C2, int M) {
    const int t = threadIdx.x;
    const int lane = t & 63;
    const int wv = t >> 6;
    const int mt0 = blockIdx.x * 2;          // two 16-row tiles per block
    const int ln15 = lane & 15;
    const int quad = lane >> 4;

    f32x4 acc[2][4] = {};

    const ushort* aPtr = Af + ((size_t)mt0 * 16) * 512 + (size_t)lane * 8;
    const ushort* bPtr = Bf + ((size_t)wv * 4) * 512 + (size_t)lane * 8;

    short8 aC[2], bC[4];
    #pragma unroll
    for (int mt = 0; mt < 2; mt++)
        aC[mt] = *reinterpret_cast<const short8*>(aPtr + (size_t)mt * 16 * 512);
    #pragma unroll
    for (int nt = 0; nt < 4; nt++)
        bC[nt] = *reinterpret_cast<const short8*>(bPtr + (size_t)nt * 512);

    for (int k0i = 0; k0i < 16; k0i++) {
        short8 aN[2], bN[4];
        if (k0i < 15) {
            #pragma unroll
            for (int mt = 0; mt < 2; mt++)
                aN[mt] = *reinterpret_cast<const short8*>(aPtr + ((size_t)mt * 16 + k0i + 1) * 512);
            #pragma unroll
            for (int nt = 0; nt < 4; nt++)
                bN[nt] = *reinterpret_cast<const short8*>(bPtr + ((size_t)(k0i + 1) * 16 + nt) * 512);
        }
        #pragma unroll
        for (int mt = 0; mt < 2; mt++)
            #pragma unroll
            for (int nt = 0; nt < 4; nt++)
                acc[mt][nt] = __builtin_amdgcn_mfma_f32_16x16x32_bf16(aC[mt], bC[nt], acc[mt][nt], 0, 0, 0);
        if (k0i < 15) {
            #pragma unroll
            for (int mt = 0; mt < 2; mt++) aC[mt] = aN[mt];
            #pragma unroll
            for (int nt = 0; nt < 4; nt++) bC[nt] = bN[nt];
        }
    }

    #pragma unroll
    for (int mt = 0; mt < 2; mt++) {
        float dn[4];
        #pragma unroll
        for (int r = 0; r < 4; r++) {
            int gm = (mt0 + mt) * 16 + quad * 4 + r;
            dn[r] = (gm < M) ? dis[gm] : 0.f;
        }
        #pragma unroll
        for (int nt = 0; nt < 4; nt++) {
            int gn = wv * 64 + nt * 16 + ln15;   // 0..255
            #pragma unroll
            for (int r = 0; r < 4; r++) {
                int gm = (mt0 + mt) * 16 + quad * 4 + r;
                if (gm >= M) continue;
                float v = acc[mt][nt][r];
                if (gn < 128) {
                    C1[(size_t)gm * 128 + gn] = fmaxf(v + bias1[gn], 0.f);
                } else {
                    C2[(size_t)gm * 128 + (gn - 128)] = bf16_bits(v * dn[r]);
                }
            }
        }
    }
}

extern "C" void kernel_launch(void* const* d_in, const int* in_sizes, int n_in,
                              void* d_out, int out_size, void* d_ws, size_t ws_size,
                              hipStream_t stream) {
    const float* x       = (const float*)d_in[0];
    const int*   ei      = (const int*)d_in[1];
    const float* w_fc    = (const float*)d_in[2];
    const float* b_fc    = (const float*)d_in[3];
    const float* w_conv1 = (const float*)d_in[4];
    const float* b_conv1 = (const float*)d_in[5];
    const float* w_fc1   = (const float*)d_in[6];
    const float* b_fc1   = (const float*)d_in[7];
    const float* w_conv2 = (const float*)d_in[8];
    const float* b_conv2 = (const float*)d_in[9];
    const float* w_fc2   = (const float*)d_in[10];
    const float* b_fc2   = (const float*)d_in[11];
    const float* w_conv3 = (const float*)d_in[12];
    const float* b_conv3 = (const float*)d_in[13];

    const int N = in_sizes[0] / 64;       // 50000
    const int E = in_sizes[1] / 2;        // 800000
    const int* row = ei;
    const int* col = ei + E;

    const int nb = (N + 255) / 256;       // 196 buckets
    const int nblk = (N + 63) / 64;       // 782  (64-row blocks, mm64)
    const int nblk2 = (N + 31) / 32;      // 1563 (32-row blocks, gemm2)
    const int Mt = nblk * 4;              // 3128 row-tiles of 16

    // workspace layout. alloc() takes 4-BYTE units (chunks padded to 16B).
    char* p = (char*)d_ws;
    auto alloc = [&](size_t elems) {
        void* q = p; p += ((elems + 3) & ~(size_t)3) * 4; return q;
    };
    int*    bcnt    = (int*)   alloc(200);
    int*    bbase   = (int*)   alloc(200);
    int*    bcur    = (int*)   alloc(200);
    int*    rowptr  = (int*)   alloc(N + 4);
    uint*   stage   = (uint*)  alloc(E);                   // packed (col<<16|row)
    ushort* csr16   = (ushort*)alloc((size_t)E / 2);       // 2B row index per edge
    float*  dis     = (float*) alloc(N);
    ushort* xh      = (ushort*)alloc((size_t)N * 32);      // N*64 bf16 = N*32 words
    ushort* xl      = (ushort*)alloc((size_t)N * 32);
    ushort* xs      = (ushort*)alloc((size_t)N * 32);      // dis-scaled gather copy
    ushort* agghi   = (ushort*)alloc((size_t)N * 32);
    ushort* agglo   = (ushort*)alloc((size_t)N * 32);
    ushort* x3f     = (ushort*)alloc((size_t)Mt * 4096);   // hi only: Mt*16*64*8 ushorts
    ushort* Bf      = (ushort*)alloc(65536);               // single bf16
    ushort* W0f     = (ushort*)alloc(16384);
    ushort* W1f     = (ushort*)alloc(16384);
    float*  x5      = (float*) alloc((size_t)N * 128);
    ushort* xw2     = (ushort*)alloc((size_t)N * 64);      // N*128 bf16
    float*  xw3     = (float*) alloc(N);

    float* out = (float*)d_out;

    // ---- CSR build (count-free) ----
    hipMemsetAsync(bcnt, 0, 196 * sizeof(int), stream);
    k_bcount<<<(E + 2047) / 2048, 256, 0, stream>>>(col, bcnt, E);
    k_bscan<<<1, 256, 0, stream>>>(bcnt, bbase, bcur, E);
    k_binA<<<(E + 2047) / 2048, 256, 0, stream>>>(row, col, bcur, stage, E);
    k_binB<<<nb, 256, 0, stream>>>(stage, bbase, rowptr, dis, csr16, N, E);

    // input split (+dis-scaled copy) + weight fragment packing
    k_prepX<<<(N * 16 + 255) / 256, 256, 0, stream>>>(x, dis, xh, xl, xs, N * 16);
    k_prepW<<<24576 / 256, 256, 0, stream>>>(w_fc, w_conv1, w_fc1, w_conv2,
                                             W0f, W1f, Bf);

    // conv1 propagate: agg = dis[col] * sum xs[row], wide-granule gather
    k_agg64_csr<<<(N + 3) / 4, 256, 0, stream>>>(xs, rowptr, csr16, dis, agghi, agglo, N);

    // x1/x2 layers via MFMA -> x3f fragments (single bf16)
    k_mm64<<<dim3(nblk, 2), 256, 0, stream>>>(xh, xl, agghi, agglo, W0f, W1f,
                                              b_fc, b_conv1, x3f, N);

    // x5 = relu(x3 @ w_fc1 + b_fc1) ; xw2 = dis * (x3 @ w_conv2) (bf16 MFMA)
    k_gemm2_mfma<<<nblk2, 256, 0, stream>>>(x3f, Bf, b_fc1, dis, x5, xw2, N);

    // x7 in registers (wide-granule gather); fused dual dot -> out, xw3
    k_agg128_x7dot<<<(N + 3) / 4, 256, 0, stream>>>(
        xw2, rowptr, csr16, dis, b_conv2, x5,
        w_fc2, b_fc2, w_conv3, b_conv3, out, xw3, N);

    // out += dis[i] * sum xw3[row]
    k_agg1_csr<<<(N + 255) / 256, 256, 0, stream>>>(xw3, rowptr, csr16, dis, out, N);
}

// Round 19
// 269.628 us; speedup vs baseline: 1.6790x; 1.0319x over previous
//
#include <hip/hip_runtime.h>
#include <hip/hip_bf16.h>

typedef __attribute__((ext_vector_type(8))) short short8;
typedef __attribute__((ext_vector_type(4))) float f32x4;

__device__ __forceinline__ ushort bf16_bits(float v) {
    __hip_bfloat16 h = __float2bfloat16(v);
    return *reinterpret_cast<ushort*>(&h);
}
__device__ __forceinline__ float bf16_val(float v) {
    __hip_bfloat16 h = __float2bfloat16(v);
    return __bfloat162float(h);
}
__device__ __forceinline__ float bfu_lo(uint u) {
    uint t = u << 16; return __uint_as_float(t);
}
__device__ __forceinline__ float bfu_hi(uint u) {
    uint t = u & 0xffff0000u; return __uint_as_float(t);
}

// ---------------- CSR build (count-free: degrees computed in binB) ----------------

__global__ __launch_bounds__(256) void k_bcount(const int* __restrict__ col,
                                                int* __restrict__ bcnt, int E) {
    __shared__ int hist[196];
    int tid = threadIdx.x;
    int base = blockIdx.x * 2048;
    if (tid < 196) hist[tid] = 0;
    __syncthreads();
    #pragma unroll
    for (int i = 0; i < 8; i++) {
        int e = base + i * 256 + tid;
        if (e < E) atomicAdd(&hist[col[e] >> 8], 1);
    }
    __syncthreads();
    if (tid < 196 && hist[tid] > 0) atomicAdd(&bcnt[tid], hist[tid]);
}

__global__ __launch_bounds__(256) void k_bscan(const int* __restrict__ bcnt,
                                               int* __restrict__ bbase,
                                               int* __restrict__ bcur, int E) {
    int i = threadIdx.x;
    int v = (i < 196) ? bcnt[i] : 0;
    int lane = i & 63, w = i >> 6;
    int s = v;
    #pragma unroll
    for (int o = 1; o < 64; o <<= 1) {
        int t = __shfl_up(s, o);
        if (lane >= o) s += t;
    }
    __shared__ int wsum[4];
    if (lane == 63) wsum[w] = s;
    __syncthreads();
    int add = 0;
    for (int ww = 0; ww < w; ww++) add += wsum[ww];
    int excl = s + add - v;
    if (i < 196) {
        bbase[i] = excl;
        bcur[i] = excl;
    }
    if (i == 195) bbase[196] = excl + v;   // == E
}

__global__ __launch_bounds__(256) void k_binA(const int* __restrict__ row,
                                              const int* __restrict__ col,
                                              int* __restrict__ bcur,
                                              uint* __restrict__ stage, int E) {
    __shared__ uint colbuf[2048];
    __shared__ int hist[196];
    __shared__ int lcur[196];
    int tid = threadIdx.x;
    int base = blockIdx.x * 2048;
    if (tid < 196) hist[tid] = 0;
    __syncthreads();
    #pragma unroll
    for (int i = 0; i < 8; i++) {
        int e = base + i * 256 + tid;
        uint c = 0xFFFFFFFFu;
        if (e < E) {
            c = (uint)col[e];
            atomicAdd(&hist[c >> 8], 1);
        }
        colbuf[i * 256 + tid] = c;
    }
    __syncthreads();
    if (tid < 196 && hist[tid] > 0) lcur[tid] = atomicAdd(&bcur[tid], hist[tid]);
    __syncthreads();
    #pragma unroll
    for (int i = 0; i < 8; i++) {
        int idx = i * 256 + tid;
        uint c = colbuf[idx];
        if (c != 0xFFFFFFFFu) {
            uint r = (uint)row[base + idx];
            int p = atomicAdd(&lcur[c >> 8], 1);
            stage[p] = (c << 16) | r;
        }
    }
}

__global__ __launch_bounds__(256) void k_binB(const uint* __restrict__ stage,
                                              const int* __restrict__ bbase,
                                              int* __restrict__ rowptr,
                                              float* __restrict__ dis,
                                              ushort* __restrict__ csr16,
                                              int n, int E) {
    __shared__ int cnt[256];
    __shared__ int cur[256];
    __shared__ int wsum[4];
    int b = blockIdx.x;
    int lo = b << 8;
    int tid = threadIdx.x;
    int gstart = bbase[b], gend = bbase[b + 1];
    cnt[tid] = 0;
    __syncthreads();
    for (int idx = gstart + tid; idx < gend; idx += 256)
        atomicAdd(&cnt[(stage[idx] >> 16) & 255], 1);
    __syncthreads();
    int v = cnt[tid];
    int lane = tid & 63, w = tid >> 6;
    int s = v;
    #pragma unroll
    for (int o = 1; o < 64; o <<= 1) {
        int t = __shfl_up(s, o);
        if (lane >= o) s += t;
    }
    if (lane == 63) wsum[w] = s;
    __syncthreads();
    int add = 0;
    for (int ww = 0; ww < w; ww++) add += wsum[ww];
    int excl = s + add - v + gstart;
    int node = lo + tid;
    if (node < n) {
        rowptr[node] = excl;
        dis[node] = v > 0 ? rsqrtf((float)v) : 0.f;
    }
    cur[tid] = excl;
    if (tid == 0 && b == gridDim.x - 1) rowptr[n] = E;
    __syncthreads();
    for (int idx = gstart + tid; idx < gend; idx += 256) {
        uint pk = stage[idx];
        int p = atomicAdd(&cur[(pk >> 16) & 255], 1);
        csr16[p] = (ushort)(pk & 0xffffu);
    }
}

// ---------------- input split: x -> bf16 + dis-scaled bf16 copy ----------------

__global__ __launch_bounds__(256) void k_prepX(const float* __restrict__ x,
                                               const float* __restrict__ dis,
                                               ushort* __restrict__ xh,
                                               ushort* __restrict__ xs, int total4) {
    int i = blockIdx.x * 256 + threadIdx.x;
    if (i >= total4) return;
    float4 v = reinterpret_cast<const float4*>(x)[i];
    float dn = dis[i >> 4];                  // node = (i*4)/64
    float vv[4] = {v.x, v.y, v.z, v.w};
    uint hv[2], sv[2];
    #pragma unroll
    for (int g = 0; g < 2; g++) {
        float a0 = vv[g * 2], a1 = vv[g * 2 + 1];
        hv[g] = (uint)bf16_bits(a0) | ((uint)bf16_bits(a1) << 16);
        sv[g] = (uint)bf16_bits(a0 * dn) | ((uint)bf16_bits(a1 * dn) << 16);
    }
    reinterpret_cast<uint2*>(xh)[i] = make_uint2(hv[0], hv[1]);
    reinterpret_cast<uint2*>(xs)[i] = make_uint2(sv[0], sv[1]);
}

// ---------------- CSR aggregations (gather, no atomics) ----------------

// agg[i] = dis[i] * sum_e xs[row_e], wide-granule: lane = sub(0..7)*8+li(0..7);
// uint4/lane -> 8 rows (1KB) per instruction. Output single bf16 (hi only).
__global__ __launch_bounds__(256) void k_agg64_csr(const ushort* __restrict__ xs,
                                                   const int* __restrict__ rowptr,
                                                   const ushort* __restrict__ csr16,
                                                   const float* __restrict__ dis,
                                                   ushort* __restrict__ agghi, int n) {
    int node = blockIdx.x * 4 + (threadIdx.x >> 6);
    if (node >= n) return;
    int lane = threadIdx.x & 63;
    int sub = lane >> 3;          // edge slot 0..7
    int li  = lane & 7;           // dim group: dims li*8 .. li*8+7
    int s = rowptr[node], t = rowptr[node + 1];
    float acc[8] = {};
    int p = s;
    for (; p + 16 <= t; p += 16) {
        int rr[2];
        #pragma unroll
        for (int u = 0; u < 2; u++) rr[u] = csr16[p + u * 8 + sub];
        uint4 v[2];
        #pragma unroll
        for (int u = 0; u < 2; u++)
            v[u] = *reinterpret_cast<const uint4*>(&xs[(size_t)rr[u] * 64 + li * 8]);
        #pragma unroll
        for (int u = 0; u < 2; u++) {
            acc[0] += bfu_lo(v[u].x); acc[1] += bfu_hi(v[u].x);
            acc[2] += bfu_lo(v[u].y); acc[3] += bfu_hi(v[u].y);
            acc[4] += bfu_lo(v[u].z); acc[5] += bfu_hi(v[u].z);
            acc[6] += bfu_lo(v[u].w); acc[7] += bfu_hi(v[u].w);
        }
    }
    for (; p < t; p += 8) {
        int e = p + sub;
        if (e < t) {
            int rr = csr16[e];
            uint4 v = *reinterpret_cast<const uint4*>(&xs[(size_t)rr * 64 + li * 8]);
            acc[0] += bfu_lo(v.x); acc[1] += bfu_hi(v.x);
            acc[2] += bfu_lo(v.y); acc[3] += bfu_hi(v.y);
            acc[4] += bfu_lo(v.z); acc[5] += bfu_hi(v.z);
            acc[6] += bfu_lo(v.w); acc[7] += bfu_hi(v.w);
        }
    }
    #pragma unroll
    for (int j = 0; j < 8; j++) {
        acc[j] += __shfl_xor(acc[j], 8);
        acc[j] += __shfl_xor(acc[j], 16);
        acc[j] += __shfl_xor(acc[j], 32);
    }
    if (sub == 0) {
        float dn = dis[node];
        uint hp[4];
        #pragma unroll
        for (int g = 0; g < 4; g++) {
            float a0 = acc[g * 2] * dn, a1 = acc[g * 2 + 1] * dn;
            hp[g] = (uint)bf16_bits(a0) | ((uint)bf16_bits(a1) << 16);
        }
        *reinterpret_cast<uint4*>(&agghi[(size_t)node * 64 + li * 8]) =
            make_uint4(hp[0], hp[1], hp[2], hp[3]);
    }
}

// Fused x7 + dual dot, wide-granule gather: lane = sub(0..3)*16 + li(0..15);
// uint4/lane -> 4 rows (1KB) per instruction. x5 is packed bf16.
__global__ __launch_bounds__(256) void k_agg128_x7dot(
    const ushort* __restrict__ xw,
    const int* __restrict__ rowptr,
    const ushort* __restrict__ csr16,
    const float* __restrict__ dis,
    const float* __restrict__ b2,
    const ushort* __restrict__ x5,
    const float* __restrict__ wfc2, const float* __restrict__ bfc2,
    const float* __restrict__ wc3,  const float* __restrict__ bc3,
    float* __restrict__ out, float* __restrict__ xw3, int n) {
    int node = blockIdx.x * 4 + (threadIdx.x >> 6);
    if (node >= n) return;
    int lane = threadIdx.x & 63;
    int sub = lane >> 4;          // edge slot 0..3
    int li  = lane & 15;          // dim group: dims li*8 .. li*8+7
    int s = rowptr[node], t = rowptr[node + 1];
    float acc[8] = {};
    int p = s;
    for (; p + 16 <= t; p += 16) {
        int rr[4];
        #pragma unroll
        for (int u = 0; u < 4; u++) rr[u] = csr16[p + u * 4 + sub];
        uint4 v[4];
        #pragma unroll
        for (int u = 0; u < 4; u++)
            v[u] = *reinterpret_cast<const uint4*>(&xw[(size_t)rr[u] * 128 + li * 8]);
        #pragma unroll
        for (int u = 0; u < 4; u++) {
            acc[0] += bfu_lo(v[u].x); acc[1] += bfu_hi(v[u].x);
            acc[2] += bfu_lo(v[u].y); acc[3] += bfu_hi(v[u].y);
            acc[4] += bfu_lo(v[u].z); acc[5] += bfu_hi(v[u].z);
            acc[6] += bfu_lo(v[u].w); acc[7] += bfu_hi(v[u].w);
        }
    }
    for (; p < t; p += 4) {
        int e = p + sub;
        if (e < t) {
            int rr = csr16[e];
            uint4 v = *reinterpret_cast<const uint4*>(&xw[(size_t)rr * 128 + li * 8]);
            acc[0] += bfu_lo(v.x); acc[1] += bfu_hi(v.x);
            acc[2] += bfu_lo(v.y); acc[3] += bfu_hi(v.y);
            acc[4] += bfu_lo(v.z); acc[5] += bfu_hi(v.z);
            acc[6] += bfu_lo(v.w); acc[7] += bfu_hi(v.w);
        }
    }
    #pragma unroll
    for (int j = 0; j < 8; j++) {
        acc[j] += __shfl_xor(acc[j], 16);
        acc[j] += __shfl_xor(acc[j], 32);
    }
    float dn = dis[node];
    float s1 = 0.f, s2 = 0.f;
    if (sub == 0) {
        uint4 xv = *reinterpret_cast<const uint4*>(&x5[(size_t)node * 128 + li * 8]);
        float xr[8] = {bfu_lo(xv.x), bfu_hi(xv.x), bfu_lo(xv.y), bfu_hi(xv.y),
                       bfu_lo(xv.z), bfu_hi(xv.z), bfu_lo(xv.w), bfu_hi(xv.w)};
        #pragma unroll
        for (int j = 0; j < 8; j++) {
            int d = li * 8 + j;
            float x7 = xr[j] + fmaxf(dn * acc[j] + b2[d], 0.f);
            s1 += x7 * wfc2[d];
            s2 += x7 * wc3[d];
        }
    }
    #pragma unroll
    for (int o = 32; o > 0; o >>= 1) {
        s1 += __shfl_down(s1, o);
        s2 += __shfl_down(s2, o);
    }
    if (lane == 0) {
        out[node] = s1 + bfc2[0] + bc3[0];
        xw3[node] = s2 * dn;                   // pre-scale for agg1
    }
}

__global__ __launch_bounds__(256) void k_agg1_csr(const float* __restrict__ sv,
                                                  const int* __restrict__ rowptr,
                                                  const ushort* __restrict__ csr16,
                                                  const float* __restrict__ dis,
                                                  float* __restrict__ out, int n) {
    int i = blockIdx.x * 256 + threadIdx.x;
    if (i >= n) return;
    int s = rowptr[i], t = rowptr[i + 1];
    float a = 0.f;
    #pragma unroll 4
    for (int p = s; p < t; ++p) a += sv[csr16[p]];
    out[i] += dis[i] * a;
}

// ---------------- weight fragment packing (single merged launch) ----------------
__global__ __launch_bounds__(256) void k_prepW(const float* __restrict__ w0,
                                               const float* __restrict__ w1,
                                               const float* __restrict__ wf1,
                                               const float* __restrict__ wf2,
                                               ushort* __restrict__ W0f,
                                               ushort* __restrict__ W1f,
                                               ushort* __restrict__ Bf) {
    int id = blockIdx.x * 256 + threadIdx.x;   // 8192 + 16384 = 24576
    if (id < 8192) {
        int mat = id >> 12;
        int rem = id & 4095;                   // arr*2048 + k0i*1024 + nt*64 + lane
        int lane = rem & 63;
        int nt = (rem >> 6) & 15;
        int k0i = (rem >> 10) & 1;
        int arr = rem >> 11;
        const float* w = mat ? w1 : w0;
        ushort* dst = mat ? W1f : W0f;
        int n = nt * 16 + (lane & 15);
        int kb = k0i * 32 + (lane >> 4) * 8;
        ushort o[8];
        #pragma unroll
        for (int j = 0; j < 8; j++) {
            float v = w[(size_t)(kb + j) * 256 + n];
            o[j] = arr ? bf16_bits(v - bf16_val(v)) : bf16_bits(v);
        }
        *reinterpret_cast<int4*>(&dst[(size_t)rem * 8]) = *reinterpret_cast<const int4*>(o);
    } else if (id < 24576) {
        int rem = id - 8192;                   // 16*16*64
        int lane = rem & 63;
        int nt   = (rem >> 6) & 15;
        int k0i  = (rem >> 10) & 15;
        int n = nt * 16 + (lane & 15);
        int kbase = k0i * 32 + (lane >> 4) * 8;
        ushort outv[8];
        #pragma unroll
        for (int j = 0; j < 8; j++) {
            int k = kbase + j;
            float v = (n < 128) ? wf1[(size_t)k * 128 + n]
                                : wf2[(size_t)k * 128 + (n - 128)];
            outv[j] = bf16_bits(v);
        }
        *reinterpret_cast<int4*>(&Bf[(size_t)rem * 8]) = *reinterpret_cast<const int4*>(outv);
    }
}

// ---------------- MFMA GEMMs ----------------

// K=64 dual-layer MFMA GEMM (blockIdx.y = layer), 2-term split:
// A single bf16 (xh / agghi), weights hi+lo.
__global__ __launch_bounds__(256) void k_mm64(
    const ushort* __restrict__ xh, const ushort* __restrict__ ah_,
    const ushort* __restrict__ W0f, const ushort* __restrict__ W1f,
    const float* __restrict__ b0, const float* __restrict__ b1,
    ushort* __restrict__ Af, int M) {
    const int layer = blockIdx.y;
    const ushort* A = layer ? ah_ : xh;
    const ushort* Wf = layer ? W1f : W0f;
    const float* bias = layer ? b1 : b0;
    const int colbase = layer * 256;

    const int t = threadIdx.x;
    const int lane = t & 63;
    const int wv = t >> 6;
    const int m0 = blockIdx.x * 64;
    const int ln15 = lane & 15;
    const int quad = lane >> 4;

    f32x4 acc[4][4] = {};

    #pragma unroll
    for (int k0i = 0; k0i < 2; k0i++) {
        short8 bh[4], bl[4];
        #pragma unroll
        for (int nt4 = 0; nt4 < 4; nt4++) {
            const ushort* pw = Wf + ((size_t)k0i * 16 + wv * 4 + nt4) * 512 + (size_t)lane * 8;
            bh[nt4] = *reinterpret_cast<const short8*>(pw);
            bl[nt4] = *reinterpret_cast<const short8*>(pw + 16384);   // arr=1 offset
        }
        #pragma unroll
        for (int mt = 0; mt < 4; mt++) {
            int gm = m0 + mt * 16 + ln15;
            int gmc = gm < M - 1 ? gm : M - 1;   // clamp: avoid OOB reads on tail rows
            size_t ia = (size_t)gmc * 64 + k0i * 32 + quad * 8;
            short8 a = *reinterpret_cast<const short8*>(&A[ia]);
            #pragma unroll
            for (int nt4 = 0; nt4 < 4; nt4++) {
                acc[mt][nt4] = __builtin_amdgcn_mfma_f32_16x16x32_bf16(a, bh[nt4], acc[mt][nt4], 0, 0, 0);
                acc[mt][nt4] = __builtin_amdgcn_mfma_f32_16x16x32_bf16(a, bl[nt4], acc[mt][nt4], 0, 0, 0);
            }
        }
    }

    // epilogue: C layout col=lane&15, row=quad*4+r -> x3f fragment scatter (hi only)
    #pragma unroll
    for (int mt = 0; mt < 4; mt++) {
        #pragma unroll
        for (int nt4 = 0; nt4 < 4; nt4++) {
            int gn = wv * 64 + nt4 * 16 + ln15;      // local col 0..255
            int gcol = gn + colbase;                 // x3 col 0..511
            int k0f = gcol >> 5, qf = (gcol >> 3) & 3, j = gcol & 7;
            #pragma unroll
            for (int r = 0; r < 4; r++) {
                int gm = m0 + mt * 16 + quad * 4 + r;
                float v = fmaxf(acc[mt][nt4][r] + bias[gn], 0.f);
                size_t base = (((size_t)(gm >> 4)) * 16 + k0f) * 512 + (size_t)(qf * 16 + (gm & 15)) * 8 + j;
                Af[base] = bf16_bits(v);
            }
        }
    }
}

// LDS-free pure-bf16 MFMA dual GEMM, 32-row blocks, A and B register
// double-buffered. C1 (x5) now packed bf16.
__global__ __launch_bounds__(256) void k_gemm2_mfma(
    const ushort* __restrict__ Af, const ushort* __restrict__ Bf,
    const float* __restrict__ bias1, const float* __restrict__ dis,
    ushort* __restrict__ C1, ushort* __restrict__ C2, int M) {
    const int t = threadIdx.x;
    const int lane = t & 63;
    const int wv = t >> 6;
    const int mt0 = blockIdx.x * 2;          // two 16-row tiles per block
    const int ln15 = lane & 15;
    const int quad = lane >> 4;

    f32x4 acc[2][4] = {};

    const ushort* aPtr = Af + ((size_t)mt0 * 16) * 512 + (size_t)lane * 8;
    const ushort* bPtr = Bf + ((size_t)wv * 4) * 512 + (size_t)lane * 8;

    short8 aC[2], bC[4];
    #pragma unroll
    for (int mt = 0; mt < 2; mt++)
        aC[mt] = *reinterpret_cast<const short8*>(aPtr + (size_t)mt * 16 * 512);
    #pragma unroll
    for (int nt = 0; nt < 4; nt++)
        bC[nt] = *reinterpret_cast<const short8*>(bPtr + (size_t)nt * 512);

    for (int k0i = 0; k0i < 16; k0i++) {
        short8 aN[2], bN[4];
        if (k0i < 15) {
            #pragma unroll
            for (int mt = 0; mt < 2; mt++)
                aN[mt] = *reinterpret_cast<const short8*>(aPtr + ((size_t)mt * 16 + k0i + 1) * 512);
            #pragma unroll
            for (int nt = 0; nt < 4; nt++)
                bN[nt] = *reinterpret_cast<const short8*>(bPtr + ((size_t)(k0i + 1) * 16 + nt) * 512);
        }
        #pragma unroll
        for (int mt = 0; mt < 2; mt++)
            #pragma unroll
            for (int nt = 0; nt < 4; nt++)
                acc[mt][nt] = __builtin_amdgcn_mfma_f32_16x16x32_bf16(aC[mt], bC[nt], acc[mt][nt], 0, 0, 0);
        if (k0i < 15) {
            #pragma unroll
            for (int mt = 0; mt < 2; mt++) aC[mt] = aN[mt];
            #pragma unroll
            for (int nt = 0; nt < 4; nt++) bC[nt] = bN[nt];
        }
    }

    #pragma unroll
    for (int mt = 0; mt < 2; mt++) {
        float dn[4];
        #pragma unroll
        for (int r = 0; r < 4; r++) {
            int gm = (mt0 + mt) * 16 + quad * 4 + r;
            dn[r] = (gm < M) ? dis[gm] : 0.f;
        }
        #pragma unroll
        for (int nt = 0; nt < 4; nt++) {
            int gn = wv * 64 + nt * 16 + ln15;   // 0..255
            #pragma unroll
            for (int r = 0; r < 4; r++) {
                int gm = (mt0 + mt) * 16 + quad * 4 + r;
                if (gm >= M) continue;
                float v = acc[mt][nt][r];
                if (gn < 128) {
                    C1[(size_t)gm * 128 + gn] = bf16_bits(fmaxf(v + bias1[gn], 0.f));
                } else {
                    C2[(size_t)gm * 128 + (gn - 128)] = bf16_bits(v * dn[r]);
                }
            }
        }
    }
}

extern "C" void kernel_launch(void* const* d_in, const int* in_sizes, int n_in,
                              void* d_out, int out_size, void* d_ws, size_t ws_size,
                              hipStream_t stream) {
    const float* x       = (const float*)d_in[0];
    const int*   ei      = (const int*)d_in[1];
    const float* w_fc    = (const float*)d_in[2];
    const float* b_fc    = (const float*)d_in[3];
    const float* w_conv1 = (const float*)d_in[4];
    const float* b_conv1 = (const float*)d_in[5];
    const float* w_fc1   = (const float*)d_in[6];
    const float* b_fc1   = (const float*)d_in[7];
    const float* w_conv2 = (const float*)d_in[8];
    const float* b_conv2 = (const float*)d_in[9];
    const float* w_fc2   = (const float*)d_in[10];
    const float* b_fc2   = (const float*)d_in[11];
    const float* w_conv3 = (const float*)d_in[12];
    const float* b_conv3 = (const float*)d_in[13];

    const int N = in_sizes[0] / 64;       // 50000
    const int E = in_sizes[1] / 2;        // 800000
    const int* row = ei;
    const int* col = ei + E;

    const int nb = (N + 255) / 256;       // 196 buckets
    const int nblk = (N + 63) / 64;       // 782  (64-row blocks, mm64)
    const int nblk2 = (N + 31) / 32;      // 1563 (32-row blocks, gemm2)
    const int Mt = nblk * 4;              // 3128 row-tiles of 16

    // workspace layout. alloc() takes 4-BYTE units (chunks padded to 16B).
    char* p = (char*)d_ws;
    auto alloc = [&](size_t elems) {
        void* q = p; p += ((elems + 3) & ~(size_t)3) * 4; return q;
    };
    int*    bcnt    = (int*)   alloc(200);
    int*    bbase   = (int*)   alloc(200);
    int*    bcur    = (int*)   alloc(200);
    int*    rowptr  = (int*)   alloc(N + 4);
    uint*   stage   = (uint*)  alloc(E);                   // packed (col<<16|row)
    ushort* csr16   = (ushort*)alloc((size_t)E / 2);       // 2B row index per edge
    float*  dis     = (float*) alloc(N);
    ushort* xh      = (ushort*)alloc((size_t)N * 32);      // N*64 bf16 = N*32 words
    ushort* xs      = (ushort*)alloc((size_t)N * 32);      // dis-scaled gather copy
    ushort* agghi   = (ushort*)alloc((size_t)N * 32);
    ushort* x3f     = (ushort*)alloc((size_t)Mt * 4096);   // hi only: Mt*16*64*8 ushorts
    ushort* Bf      = (ushort*)alloc(65536);               // single bf16
    ushort* W0f     = (ushort*)alloc(16384);
    ushort* W1f     = (ushort*)alloc(16384);
    ushort* x5      = (ushort*)alloc((size_t)N * 64);      // N*128 bf16
    ushort* xw2     = (ushort*)alloc((size_t)N * 64);      // N*128 bf16
    float*  xw3     = (float*) alloc(N);

    float* out = (float*)d_out;

    // ---- CSR build (count-free) ----
    hipMemsetAsync(bcnt, 0, 196 * sizeof(int), stream);
    k_bcount<<<(E + 2047) / 2048, 256, 0, stream>>>(col, bcnt, E);
    k_bscan<<<1, 256, 0, stream>>>(bcnt, bbase, bcur, E);
    k_binA<<<(E + 2047) / 2048, 256, 0, stream>>>(row, col, bcur, stage, E);
    k_binB<<<nb, 256, 0, stream>>>(stage, bbase, rowptr, dis, csr16, N, E);

    // input split (+dis-scaled copy) + weight fragment packing
    k_prepX<<<(N * 16 + 255) / 256, 256, 0, stream>>>(x, dis, xh, xs, N * 16);
    k_prepW<<<24576 / 256, 256, 0, stream>>>(w_fc, w_conv1, w_fc1, w_conv2,
                                             W0f, W1f, Bf);

    // conv1 propagate: agg = dis[col] * sum xs[row], wide-granule gather
    k_agg64_csr<<<(N + 3) / 4, 256, 0, stream>>>(xs, rowptr, csr16, dis, agghi, N);

    // x1/x2 layers via MFMA -> x3f fragments (single bf16, 2-term)
    k_mm64<<<dim3(nblk, 2), 256, 0, stream>>>(xh, agghi, W0f, W1f,
                                              b_fc, b_conv1, x3f, N);

    // x5 = relu(x3 @ w_fc1 + b_fc1) (bf16) ; xw2 = dis * (x3 @ w_conv2) (bf16)
    k_gemm2_mfma<<<nblk2, 256, 0, stream>>>(x3f, Bf, b_fc1, dis, x5, xw2, N);

    // x7 in registers (wide-granule gather); fused dual dot -> out, xw3
    k_agg128_x7dot<<<(N + 3) / 4, 256, 0, stream>>>(
        xw2, rowptr, csr16, dis, b_conv2, x5,
        w_fc2, b_fc2, w_conv3, b_conv3, out, xw3, N);

    // out += dis[i] * sum xw3[row]
    k_agg1_csr<<<(N + 255) / 256, 256, 0, stream>>>(xw3, rowptr, csr16, dis, out, N);
}